// Round 7
// baseline (2190.742 us; speedup 1.0000x reference)
//
#include <hip/hip_runtime.h>
#include <math.h>

// FAENet forward. All GEMMs via bf16 MFMA (16x16x32), fp32 accumulate.
// KEY LAYOUT TRICK (r3): mfma operands SWAPPED -> mfma(W_frag, A_frag, acc).
// Lane holds 1 output row x 4 CONSECUTIVE cols -> vectorized epilogues.
// r6: REVERT r5's 1x4 wave split (regressed: redundant A loads quadruplicated
// L1 requests). mgemm back to 2x2. NEW: msg_agg fuses geom GEMM + el*hd[src]
// + dst-segment-sum (replaces el materialization + csr_gather): el tile lives
// only in LDS; per-dst segments flushed with f32 atomics into memset agg.
// Kills 410 MB/layer of el write+read traffic.
// r4: build_eapad pre-pass -> edge stage-1 A loads direct from global.
// out_reduce: contiguous per-wave chunks over sorted batch (~2K atomics).
// silu: v_rcp_f32 instead of IEEE divide (~1ulp; bf16 output absorbs it).

#define EPS_GN 1e-5f

typedef __attribute__((ext_vector_type(8))) short bf16x8;
typedef __attribute__((ext_vector_type(4))) float f32x4;

__device__ __forceinline__ float silu_f(float x) {
    float e = __expf(-x);
    return x * __builtin_amdgcn_rcpf(1.0f + e);
}
__device__ __forceinline__ float bf2f(unsigned int u) {
    union { unsigned int i; float f; } c;
    c.i = u << 16;
    return c.f;
}
__device__ __forceinline__ unsigned int f2bf(float x) {
    union { float f; unsigned int i; } c;
    c.f = x;
    unsigned int r = c.i + 0x7fffu + ((c.i >> 16) & 1u);
    return r >> 16;
}

enum { A_BF16 = 0, A_F32 = 1 };
enum { ME_STORE_F32 = 0, ME_STORE_BF16 = 1, ME_PERM_BF16 = 2, ME_RESID = 3 };

// C[M x NFTOT] = epi(A[M x K] @ W[NFTOT x K]^T + bias), MFMA bf16.
// acc[tm][tn] layout (operand-swapped): lane row = 16*tm + l16,
// cols = 16*tn + quad*4 + rg (4 consecutive features per lane).
// NOTE: ME_STORE_BF16 / ME_PERM_BF16 require NFTOT==128 and gridDim.y==1.
template<int K, int AMODE, int EPI, bool PRELW>
__global__ __launch_bounds__(256)
void mgemm(const void* __restrict__ Ap, const unsigned short* __restrict__ Wp,
           const float* __restrict__ bias, float* __restrict__ Cf,
           unsigned short* __restrict__ Cb, int M, int NFTOT,
           const int* __restrict__ perm)
{
    constexpr int KS = K / 32;
    const int tid = threadIdx.x;
    const int lane = tid & 63;
    const int wv = tid >> 6;                    // 0..3
    const int l16 = lane & 15;
    const int quad = lane >> 4;                 // 0..3
    const int m0 = blockIdx.x * 128 + (wv >> 1) * 64;
    const int n0 = blockIdx.y * 128 + (wv & 1) * 64;

    bf16x8 wpre[PRELW ? (KS * 4) : 1];
    if (PRELW) {
#pragma unroll
        for (int t = 0; t < 4; ++t)
#pragma unroll
            for (int s = 0; s < KS; ++s)
                wpre[t * KS + s] = *(const bf16x8*)(Wp +
                    (size_t)(n0 + 16 * t + l16) * K + s * 32 + quad * 8);
    }

    f32x4 acc[4][4];
#pragma unroll
    for (int i = 0; i < 4; ++i)
#pragma unroll
        for (int j = 0; j < 4; ++j) acc[i][j] = (f32x4){0.f, 0.f, 0.f, 0.f};

    for (int s = 0; s < KS; ++s) {
        bf16x8 af[4];
#pragma unroll
        for (int t = 0; t < 4; ++t) {
            int r = m0 + 16 * t + l16;
            if (r >= M) r = M - 1;
            if (AMODE == A_BF16) {
                af[t] = *(const bf16x8*)((const unsigned short*)Ap +
                                         (size_t)r * K + s * 32 + quad * 8);
            } else {
                const float* ap = (const float*)Ap + (size_t)r * K + s * 32 + quad * 8;
                float4 x0 = *(const float4*)ap;
                float4 x1 = *(const float4*)(ap + 4);
                bf16x8 v;
                v[0] = (short)f2bf(x0.x); v[1] = (short)f2bf(x0.y);
                v[2] = (short)f2bf(x0.z); v[3] = (short)f2bf(x0.w);
                v[4] = (short)f2bf(x1.x); v[5] = (short)f2bf(x1.y);
                v[6] = (short)f2bf(x1.z); v[7] = (short)f2bf(x1.w);
                af[t] = v;
            }
        }
        bf16x8 wf[4];
#pragma unroll
        for (int t = 0; t < 4; ++t) {
            if (PRELW) wf[t] = wpre[t * KS + s];
            else       wf[t] = *(const bf16x8*)(Wp +
                           (size_t)(n0 + 16 * t + l16) * K + s * 32 + quad * 8);
        }
#pragma unroll
        for (int tm = 0; tm < 4; ++tm)
#pragma unroll
            for (int tn = 0; tn < 4; ++tn)
                acc[tm][tn] = __builtin_amdgcn_mfma_f32_16x16x32_bf16(
                    wf[tn], af[tm], acc[tm][tn], 0, 0, 0);
    }

    if constexpr (EPI == ME_STORE_BF16 || EPI == ME_PERM_BF16) {
        // silu -> LDS (quad-XOR swizzle, b64 writes) -> cooperative row
        // store: each wave stores 32 full 256B rows, 16B/lane, full 64B lines.
        __shared__ unsigned short sOut[128 * 128];
        const int mwl = (wv >> 1) * 64;
        const int nwl = (wv & 1) * 64;
        const int key = (l16 >> 2) & 3;   // == (local_row>>2)&3
#pragma unroll
        for (int tn = 0; tn < 4; ++tn) {
            int cb = nwl + 16 * tn + quad * 4;
            float4 bv = *(const float4*)(bias + cb);
            int cs = cb ^ (key << 4);
#pragma unroll
            for (int tm = 0; tm < 4; ++tm) {
                int r = mwl + 16 * tm + l16;
                ushort4 pk;
                pk.x = (unsigned short)f2bf(silu_f(acc[tm][tn][0] + bv.x));
                pk.y = (unsigned short)f2bf(silu_f(acc[tm][tn][1] + bv.y));
                pk.z = (unsigned short)f2bf(silu_f(acc[tm][tn][2] + bv.z));
                pk.w = (unsigned short)f2bf(silu_f(acc[tm][tn][3] + bv.w));
                *(ushort4*)(sOut + r * 128 + cs) = pk;
            }
        }
        __syncthreads();
#pragma unroll
        for (int rr = 0; rr < 8; ++rr) {
            int r = (wv << 5) + (rr << 2) + quad;
            int gr = blockIdx.x * 128 + r;
            if (gr >= M) continue;
            int cs = (l16 * 8) ^ (((r >> 2) & 3) << 4);
            bf16x8 v = *(const bf16x8*)(sOut + r * 128 + cs);
            int dr = (EPI == ME_PERM_BF16) ? perm[gr] : gr;
            *(bf16x8*)(Cb + (size_t)dr * 128 + l16 * 8) = v;
        }
    } else {
        // f32 path: 4 consecutive cols per lane -> float4 stores (full lines).
#pragma unroll
        for (int tn = 0; tn < 4; ++tn) {
            int cb = n0 + 16 * tn + quad * 4;
            float4 bv = *(const float4*)(bias + cb);
#pragma unroll
            for (int tm = 0; tm < 4; ++tm) {
                int r = m0 + 16 * tm + l16;
                if (r >= M) continue;
                float4 v;
                v.x = silu_f(acc[tm][tn][0] + bv.x);
                v.y = silu_f(acc[tm][tn][1] + bv.y);
                v.z = silu_f(acc[tm][tn][2] + bv.z);
                v.w = silu_f(acc[tm][tn][3] + bv.w);
                float* dst = Cf + (size_t)r * NFTOT + cb;
                if (EPI == ME_STORE_F32) {
                    *(float4*)dst = v;
                } else { // ME_RESID
                    float4 o = *(const float4*)dst;
                    o.x += v.x; o.y += v.y; o.z += v.z; o.w += v.w;
                    *(float4*)dst = o;
                }
            }
        }
    }
}

// Fused interaction message pass: for a tile of 128 dst-sorted edges,
// el = silu(ebf @ gw^T + gb) computed in LDS (never materialized in HBM),
// then msg = el * hd[src_s[p]] segment-summed by dst and atomically
// accumulated into agg (pre-zeroed). Replaces geom-mgemm + csr_gather.
__global__ __launch_bounds__(256)
void msg_agg(const unsigned short* __restrict__ ebf,   // [E][128] dst-sorted
             const unsigned short* __restrict__ gw,    // [128][128] bf16
             const float* __restrict__ gb,             // [128]
             const unsigned int* __restrict__ hd2,     // hdb as u32 pairs
             const int* __restrict__ src_s,            // [E]
             const int* __restrict__ dsts,             // [E] sorted dst ids
             float* __restrict__ agg, int E)
{
    __shared__ unsigned short sOut[128 * 128];
    const int tid = threadIdx.x;
    const int lane = tid & 63;
    const int wv = tid >> 6;
    const int l16 = lane & 15;
    const int quad = lane >> 4;
    const int m0 = blockIdx.x * 128;
    const int mw = (wv >> 1) * 64;
    const int nw = (wv & 1) * 64;

    // W preload (K=128 -> 16 frags)
    bf16x8 wpre[16];
#pragma unroll
    for (int t = 0; t < 4; ++t)
#pragma unroll
        for (int s = 0; s < 4; ++s)
            wpre[t * 4 + s] = *(const bf16x8*)(gw +
                (size_t)(nw + 16 * t + l16) * 128 + s * 32 + quad * 8);

    f32x4 acc[4][4];
#pragma unroll
    for (int i = 0; i < 4; ++i)
#pragma unroll
        for (int j = 0; j < 4; ++j) acc[i][j] = (f32x4){0.f, 0.f, 0.f, 0.f};

#pragma unroll
    for (int s = 0; s < 4; ++s) {
        bf16x8 af[4];
#pragma unroll
        for (int t = 0; t < 4; ++t) {
            int r = m0 + mw + 16 * t + l16;
            if (r >= E) r = E - 1;
            af[t] = *(const bf16x8*)(ebf + (size_t)r * 128 + s * 32 + quad * 8);
        }
#pragma unroll
        for (int tm = 0; tm < 4; ++tm)
#pragma unroll
            for (int tn = 0; tn < 4; ++tn)
                acc[tm][tn] = __builtin_amdgcn_mfma_f32_16x16x32_bf16(
                    wpre[tn * 4 + s], af[tm], acc[tm][tn], 0, 0, 0);
    }

    // silu -> sOut (quad-XOR swizzle, b64 writes)
    const int key = (l16 >> 2) & 3;
#pragma unroll
    for (int tn = 0; tn < 4; ++tn) {
        int cb = nw + 16 * tn + quad * 4;
        float4 bv = *(const float4*)(gb + cb);
        int cs = cb ^ (key << 4);
#pragma unroll
        for (int tm = 0; tm < 4; ++tm) {
            int r = mw + 16 * tm + l16;
            ushort4 pk;
            pk.x = (unsigned short)f2bf(silu_f(acc[tm][tn][0] + bv.x));
            pk.y = (unsigned short)f2bf(silu_f(acc[tm][tn][1] + bv.y));
            pk.z = (unsigned short)f2bf(silu_f(acc[tm][tn][2] + bv.z));
            pk.w = (unsigned short)f2bf(silu_f(acc[tm][tn][3] + bv.w));
            *(ushort4*)(sOut + r * 128 + cs) = pk;
        }
    }
    __syncthreads();

    // segment scan: wave wv owns rows 32*wv..32*wv+31 (dst-sorted order).
    // lane holds cols (2*lane, 2*lane+1); flush per dst-segment via atomics.
    int r0 = wv * 32;
    float a0 = 0.f, a1 = 0.f;
    int p0 = m0 + r0;
    int cur = (p0 < E) ? dsts[p0] : -1;
    for (int i = 0; i < 32; ++i) {
        int r = r0 + i;
        int p = m0 + r;
        if (p >= E) break;
        int d = dsts[p];
        if (d != cur) {
            atomicAdd(&agg[(size_t)cur * 128 + 2 * lane], a0);
            atomicAdd(&agg[(size_t)cur * 128 + 2 * lane + 1], a1);
            cur = d; a0 = 0.f; a1 = 0.f;
        }
        int cs = (2 * lane) ^ (((r >> 2) & 3) << 4);
        unsigned int ev = *(const unsigned int*)(sOut + r * 128 + cs);
        unsigned int hv = hd2[(size_t)src_s[p] * 64 + lane];
        a0 = fmaf(bf2f(ev & 0xffffu), bf2f(hv & 0xffffu), a0);
        a1 = fmaf(bf2f(ev >> 16),     bf2f(hv >> 16),     a1);
    }
    if (cur >= 0) {
        atomicAdd(&agg[(size_t)cur * 128 + 2 * lane], a0);
        atomicAdd(&agg[(size_t)cur * 128 + 2 * lane + 1], a1);
    }
}

// Wcat[128 x 64] bf16 matching eapad layout [rp k=0..2 | ea k=3..52 | pad]:
// rows 0..63: le1w at cols 0..2; rows 64..127: le12w at cols 3..52; rest 0.
// bcat[128] = [le1b | le12b].
__global__ __launch_bounds__(256)
void build_wcat(const float* __restrict__ w1, const float* __restrict__ w12,
                const float* __restrict__ b1, const float* __restrict__ b12,
                unsigned short* __restrict__ wcat, float* __restrict__ bcat)
{
    int i = blockIdx.x * 256 + threadIdx.x;
    if (i < 8192) {
        int r = i >> 6, c = i & 63;
        float v = 0.f;
        if (r < 64) { if (c < 3) v = w1[r * 3 + c]; }
        else        { if (c >= 3 && c < 53) v = w12[(r - 64) * 50 + (c - 3)]; }
        wcat[i] = (unsigned short)f2bf(v);
    }
    if (i < 128) bcat[i] = (i < 64) ? b1[i] : b12[i - 64];
}

// eapad[e][0:64] = bf16([rp[e][0..2] | ea[e][0..49] | zeros]), one 16B store
// per thread (fully coalesced). Feeds stage-1 A loads directly from global.
__global__ __launch_bounds__(256)
void build_eapad(const float* __restrict__ rp, const float* __restrict__ ea,
                 unsigned short* __restrict__ out, int E)
{
    int g = blockIdx.x * 256 + threadIdx.x;     // 16B group index
    if (g >= E * 8) return;
    int e = g >> 3, sub = g & 7;
    bf16x8 v;
#pragma unroll
    for (int j = 0; j < 8; ++j) {
        int c = sub * 8 + j;
        float x = 0.f;
        if (c < 3)       x = rp[(size_t)e * 3 + c];
        else if (c < 53) x = ea[(size_t)e * 50 + (c - 3)];
        v[j] = (short)f2bf(x);
    }
    *(bf16x8*)(out + (size_t)g * 8) = v;
}

// Fused edge embedding: e[perm[r]] = silu(silu(eapad @ Wcat^T + bcat) @ W2^T + b2)
// Operand-swapped MFMA; stage-1 A direct from global; LDS = sT only (32KB).
__global__ __launch_bounds__(256)
void edge_embed_fused(const unsigned short* __restrict__ eapad,
                      const unsigned short* __restrict__ wcat,
                      const float* __restrict__ bcat,
                      const unsigned short* __restrict__ w2,
                      const float* __restrict__ b2,
                      const int* __restrict__ perm,
                      unsigned short* __restrict__ ebf, int E)
{
    __shared__ unsigned short sT[128 * 128];   // 32 KB t-tile
    const int tid = threadIdx.x;
    const int m0 = blockIdx.x * 128;

    const int lane = tid & 63;
    const int wv = tid >> 6;
    const int l16 = lane & 15, quad = lane >> 4;
    const int mw = (wv >> 1) * 64;
    const int nw = (wv & 1) * 64;

    // stage 1: t = silu(A @ Wcat^T + bcat), K=64; A fragments from global
    f32x4 acc[4][4];
#pragma unroll
    for (int i = 0; i < 4; ++i)
#pragma unroll
        for (int j = 0; j < 4; ++j) acc[i][j] = (f32x4){0.f, 0.f, 0.f, 0.f};
#pragma unroll
    for (int s = 0; s < 2; ++s) {
        bf16x8 af[4], wf[4];
#pragma unroll
        for (int t = 0; t < 4; ++t) {
            int r = m0 + mw + 16 * t + l16;
            if (r >= E) r = E - 1;
            af[t] = *(const bf16x8*)(eapad + (size_t)r * 64 + s * 32 + quad * 8);
        }
#pragma unroll
        for (int t = 0; t < 4; ++t)
            wf[t] = *(const bf16x8*)(wcat +
                (size_t)(nw + 16 * t + l16) * 64 + s * 32 + quad * 8);
#pragma unroll
        for (int tm = 0; tm < 4; ++tm)
#pragma unroll
            for (int tn = 0; tn < 4; ++tn)
                acc[tm][tn] = __builtin_amdgcn_mfma_f32_16x16x32_bf16(
                    wf[tn], af[tm], acc[tm][tn], 0, 0, 0);
    }

    // silu+bias -> sT with k-group rotation swizzle, b64 writes:
    // element (r,c) at sT[r*128 + (((c>>3)+r)&15)*8 + (c&7)]
#pragma unroll
    for (int tn = 0; tn < 4; ++tn) {
        int cb = nw + 16 * tn + quad * 4;
        float4 bv = *(const float4*)(bcat + cb);
#pragma unroll
        for (int tm = 0; tm < 4; ++tm) {
            int r = mw + 16 * tm + l16;
            int g = ((cb >> 3) + r) & 15;
            ushort4 pk;
            pk.x = (unsigned short)f2bf(silu_f(acc[tm][tn][0] + bv.x));
            pk.y = (unsigned short)f2bf(silu_f(acc[tm][tn][1] + bv.y));
            pk.z = (unsigned short)f2bf(silu_f(acc[tm][tn][2] + bv.z));
            pk.w = (unsigned short)f2bf(silu_f(acc[tm][tn][3] + bv.w));
            *(ushort4*)(sT + r * 128 + g * 8 + (cb & 7)) = pk;
        }
    }
    __syncthreads();

    // stage 2: e = silu(t @ W2^T + b2), K=128 (operand-swapped)
    f32x4 acc2[4][4];
#pragma unroll
    for (int i = 0; i < 4; ++i)
#pragma unroll
        for (int j = 0; j < 4; ++j) acc2[i][j] = (f32x4){0.f, 0.f, 0.f, 0.f};
#pragma unroll
    for (int s = 0; s < 4; ++s) {
        bf16x8 af[4], wf[4];
#pragma unroll
        for (int t = 0; t < 4; ++t) {
            int r = mw + 16 * t + l16;
            int g = (s * 4 + quad + r) & 15;
            af[t] = *(const bf16x8*)(sT + r * 128 + g * 8);
        }
#pragma unroll
        for (int t = 0; t < 4; ++t)
            wf[t] = *(const bf16x8*)(w2 +
                (size_t)(nw + 16 * t + l16) * 128 + s * 32 + quad * 8);
#pragma unroll
        for (int tm = 0; tm < 4; ++tm)
#pragma unroll
            for (int tn = 0; tn < 4; ++tn)
                acc2[tm][tn] = __builtin_amdgcn_mfma_f32_16x16x32_bf16(
                    wf[tn], af[tm], acc2[tm][tn], 0, 0, 0);
    }

    // epilogue: silu -> sT (quad-keyed XOR swizzle, b64 writes) ->
    // cooperative permuted row store (16B/lane, full 64B lines).
    __syncthreads();   // all waves done reading sT before overwrite
#pragma unroll
    for (int tn = 0; tn < 4; ++tn) {
        int cb = nw + 16 * tn + quad * 4;
        float4 bv = *(const float4*)(b2 + cb);
#pragma unroll
        for (int tm = 0; tm < 4; ++tm) {
            int r = mw + 16 * tm + l16;
            int cs = cb ^ (((r >> 2) & 3) << 4);
            ushort4 pk;
            pk.x = (unsigned short)f2bf(silu_f(acc2[tm][tn][0] + bv.x));
            pk.y = (unsigned short)f2bf(silu_f(acc2[tm][tn][1] + bv.y));
            pk.z = (unsigned short)f2bf(silu_f(acc2[tm][tn][2] + bv.z));
            pk.w = (unsigned short)f2bf(silu_f(acc2[tm][tn][3] + bv.w));
            *(ushort4*)(sT + r * 128 + cs) = pk;
        }
    }
    __syncthreads();
    // each wave stores 32 rows: quad picks row within group-of-4, l16 picks 16B chunk
#pragma unroll
    for (int rr = 0; rr < 8; ++rr) {
        int r = (wv << 5) + (rr << 2) + quad;
        int gr = m0 + r;
        if (gr >= E) continue;
        int cs = (l16 * 8) ^ (((r >> 2) & 3) << 4);
        bf16x8 v = *(const bf16x8*)(sT + r * 128 + cs);
        *(bf16x8*)(ebf + (size_t)perm[gr] * 128 + l16 * 8) = v;
    }
}

// hb0[n][0:224]=emb_w[z[n]], [224:256]=tag_emb_w[tag[n]]  (f32)
__global__ __launch_bounds__(256)
void node_gather(const int* __restrict__ z, const int* __restrict__ tag,
                 const float* __restrict__ embw, const float* __restrict__ tembw,
                 float* __restrict__ hb0, int N)
{
    int lane = threadIdx.x & 63;
    int n = blockIdx.x * 4 + (threadIdx.x >> 6);
    if (n >= N) return;
    int f = lane * 4;
    float4 v;
    if (f < 224) v = *(const float4*)(embw + (size_t)z[n] * 224 + f);
    else         v = *(const float4*)(tembw + (size_t)tag[n] * 32 + (f - 224));
    *(float4*)(hb0 + (size_t)n * 256 + f) = v;
}

// all bf16 weight conversions in one launch; dst ranges are contiguous in wbuf
__global__ __launch_bounds__(256)
void cvt_all(const float* __restrict__ le2, const float* __restrict__ geom,
             const float* __restrict__ down, const float* __restrict__ up,
             const float* __restrict__ lin, const float* __restrict__ lin2,
             const float* __restrict__ o1, unsigned short* __restrict__ dst)
{
    int i = blockIdx.x * 256 + threadIdx.x;
    if (i >= 425984) return;
    float v;
    if      (i <  16384) v = le2[i];
    else if (i <  65536) v = geom[i - 16384];
    else if (i < 163840) v = down[i - 65536];
    else if (i < 262144) v = up[i - 163840];
    else if (i < 327680) v = lin[i - 262144];
    else if (i < 393216) v = lin2[i - 327680];
    else                 v = o1[i - 393216];
    dst[i] = (unsigned short)f2bf(v);
}

// ---- counting sort by dst ----
__global__ __launch_bounds__(256)
void edge_hist(const int* __restrict__ dst, int* __restrict__ cnt, int E)
{
    for (int i = blockIdx.x * 256 + threadIdx.x; i < E; i += gridDim.x * 256)
        atomicAdd(&cnt[dst[i]], 1);
}

__global__ __launch_bounds__(1024)
void scan_excl(int* __restrict__ cnt, int N)
{
    __shared__ int sdata[1024];
    __shared__ int s_carry;
    int tid = threadIdx.x;
    if (tid == 0) s_carry = 0;
    __syncthreads();
    for (int base = 0; base < N; base += 1024) {
        int i = base + tid;
        int v = (i < N) ? cnt[i] : 0;
        sdata[tid] = v;
        __syncthreads();
        for (int off = 1; off < 1024; off <<= 1) {
            int t = (tid >= off) ? sdata[tid - off] : 0;
            __syncthreads();
            sdata[tid] += t;
            __syncthreads();
        }
        int excl = sdata[tid] - v + s_carry;
        if (i < N) cnt[i] = excl;
        int tot = sdata[1023];
        __syncthreads();
        if (tid == 0) s_carry += tot;
        __syncthreads();
    }
}

__global__ __launch_bounds__(256)
void edge_rank(const int* __restrict__ src, const int* __restrict__ dst,
               int* __restrict__ cursor, int* __restrict__ rank,
               int* __restrict__ src_s, int* __restrict__ dsts, int E)
{
    for (int i = blockIdx.x * 256 + threadIdx.x; i < E; i += gridDim.x * 256) {
        int d = dst[i];
        int p = atomicAdd(&cursor[d], 1);
        rank[i] = p;
        src_s[p] = src[i];
        dsts[p] = d;
    }
}

__global__ __launch_bounds__(256)
void gn_stats(const float* __restrict__ agg, float* __restrict__ sums, int N)
{
    __shared__ float red[512];
    int f = threadIdx.x & 127;
    int sub = threadIdx.x >> 7;
    float s = 0.f, s2 = 0.f;
    for (int r = blockIdx.x * 2 + sub; r < N; r += gridDim.x * 2) {
        float v = agg[(size_t)r * 128 + f];
        s += v;
        s2 += v * v;
    }
    red[threadIdx.x] = s;
    red[256 + threadIdx.x] = s2;
    __syncthreads();
    if (sub == 0) {
        s = red[f] + red[128 + f];
        s2 = red[256 + f] + red[384 + f];
        atomicAdd(&sums[f], s);
        atomicAdd(&sums[128 + f], s2);
    }
}

__global__ void gn_finalize(const float* __restrict__ sums,
                            const float* __restrict__ gnw, const float* __restrict__ gnb,
                            const float* __restrict__ gnms, float* __restrict__ ab,
                            float invN)
{
    int f = threadIdx.x; // 128
    float mean = sums[f] * invN;
    float ex2 = sums[128 + f] * invN;
    float m2 = mean * gnms[f];
    float var = ex2 - 2.f * m2 * mean + m2 * m2;
    float rstd = 1.0f / sqrtf(var + EPS_GN);
    float a = gnw[f] * rstd;
    ab[f] = a;
    ab[128 + f] = gnb[f] - a * m2;
}

// ga = bf16(silu(a*agg+b)) elementwise
__global__ __launch_bounds__(256)
void gn_apply(const float* __restrict__ agg, const float* __restrict__ ab,
              unsigned int* __restrict__ ga, int n2 /* N*64 */)
{
    for (int i = blockIdx.x * 256 + threadIdx.x; i < n2; i += gridDim.x * 256) {
        int f = (i & 63) * 2;
        float2 v = *(const float2*)(agg + (size_t)i * 2);
        float r0 = silu_f(ab[f] * v.x + ab[128 + f]);
        float r1 = silu_f(ab[f + 1] * v.y + ab[129 + f]);
        ga[i] = f2bf(r0) | (f2bf(r1) << 16);
    }
}

// out[g] += per-graph sum of (h1[r].w2)+b2 over sorted batch, run-accumulated.
__global__ __launch_bounds__(256)
void out_reduce(const float* __restrict__ h1, const float* __restrict__ w2,
                const float* __restrict__ b2, const int* __restrict__ batch,
                float* __restrict__ out, int N)
{
    int lane = threadIdx.x & 63;
    int wid = blockIdx.x * 4 + (threadIdx.x >> 6);
    int nwaves = gridDim.x * 4;
    int chunk = (N + nwaves - 1) / nwaves;
    int r0 = wid * chunk;
    int r1 = r0 + chunk; if (r1 > N) r1 = N;
    if (r0 >= r1) return;
    float wa = w2[lane], wb = w2[64 + lane];
    float bb = b2[0];
    int cur = batch[r0];
    float acc = 0.f;
    int cnt = 0;
    for (int r = r0; r < r1; ++r) {
        int g = batch[r];
        if (g != cur) {
            float v = acc;
#pragma unroll
            for (int o = 32; o > 0; o >>= 1) v += __shfl_down(v, o);
            if (lane == 0) atomicAdd(&out[cur], v + (float)cnt * bb);
            cur = g; acc = 0.f; cnt = 0;
        }
        acc = fmaf(h1[(size_t)r * 128 + lane], wa, acc);
        acc = fmaf(h1[(size_t)r * 128 + 64 + lane], wb, acc);
        ++cnt;
    }
    float v = acc;
#pragma unroll
    for (int o = 32; o > 0; o >>= 1) v += __shfl_down(v, o);
    if (lane == 0) atomicAdd(&out[cur], v + (float)cnt * bb);
}

extern "C" void kernel_launch(void* const* d_in, const int* in_sizes, int n_in,
                              void* d_out, int out_size, void* d_ws, size_t ws_size,
                              hipStream_t stream)
{
    const int*   z         = (const int*)d_in[0];
    const int*   tag       = (const int*)d_in[1];
    const float* rel_pos   = (const float*)d_in[2];
    const float* edge_attr = (const float*)d_in[3];
    const int*   eidx      = (const int*)d_in[4];
    const int*   batch     = (const int*)d_in[5];
    const float* le1w  = (const float*)d_in[6];
    const float* le1b  = (const float*)d_in[7];
    const float* le12w = (const float*)d_in[8];
    const float* le12b = (const float*)d_in[9];
    const float* le2w  = (const float*)d_in[10];
    const float* le2b  = (const float*)d_in[11];
    const float* embw  = (const float*)d_in[12];
    const float* tembw = (const float*)d_in[13];
    const float* linw  = (const float*)d_in[14];
    const float* linb  = (const float*)d_in[15];
    const float* lin2w = (const float*)d_in[16];
    const float* lin2b = (const float*)d_in[17];
    const float* geomw = (const float*)d_in[18];
    const float* geomb = (const float*)d_in[19];
    const float* downw = (const float*)d_in[20];
    const float* downb = (const float*)d_in[21];
    const float* upw   = (const float*)d_in[22];
    const float* upb   = (const float*)d_in[23];
    const float* gnw   = (const float*)d_in[24];
    const float* gnb   = (const float*)d_in[25];
    const float* gnms  = (const float*)d_in[26];
    const float* o1w   = (const float*)d_in[27];
    const float* o1b   = (const float*)d_in[28];
    const float* o2w   = (const float*)d_in[29];
    const float* o2b   = (const float*)d_in[30];

    const int N = in_sizes[0];
    const int E = in_sizes[2] / 3;
    const int* esrc = eidx;
    const int* edst = eidx + E;

    char* ws = (char*)d_ws;
    size_t off = 0;
    unsigned short* T = (unsigned short*)(ws + off); off += (size_t)E * 128 * 2;   // hb0+t1 / eapad
    unsigned short* ebf = (unsigned short*)(ws + off); off += (size_t)E * 128 * 2;
    float* h   = (float*)(ws + off); off += (size_t)N * 256 * 4;
    float* agg = (float*)(ws + off); off += (size_t)N * 128 * 4;
    unsigned short* hdb = (unsigned short*)(ws + off); off += (size_t)N * 128 * 2;
    int*   cnt   = (int*)(ws + off); off += (size_t)N * 4;
    int*   src_s = (int*)(ws + off); off += (size_t)E * 4;
    int*   dsts  = (int*)(ws + off); off += (size_t)E * 4;
    unsigned short* wbuf = (unsigned short*)(ws + off); off += 442368ull * 2;
    float* stats = (float*)(ws + off); off += 256 * 4;
    float* ab    = (float*)(ws + off); off += 256 * 4;
    float* bcat  = (float*)(ws + off); off += 128;

    // aliases
    unsigned short* eapad = T;                      // E*64 bf16 (dead after edge_embed)
    float* hb0 = (float*)T;                         // N*256 f32 (after edge_embed)
    float* t1  = (float*)T + (size_t)N * 256;       // N*256 f32 (dead before layers)
    int*   rank = (int*)agg;                        // E ints, dead before agg first write
    unsigned short* ga = hdb;                       // bf16 N*128, written after msg_agg
    float* h1 = agg;                                // N*128 f32, written after agg last read

    // bf16 weight buffer offsets
    unsigned short* wb_le2  = wbuf;                 // 16384
    unsigned short* wb_geom = wbuf + 16384;         // 3*16384
    unsigned short* wb_down = wbuf + 65536;         // 3*32768
    unsigned short* wb_up   = wbuf + 163840;        // 3*32768
    unsigned short* wb_lin  = wbuf + 262144;        // 65536
    unsigned short* wb_lin2 = wbuf + 327680;        // 65536
    unsigned short* wb_o1   = wbuf + 393216;        // 32768
    unsigned short* wb_cat  = wbuf + 425984;        // 8192

    const int mbE = (E + 127) / 128;
    const int mbN = (N + 127) / 128;
    dim3 blk(256);

    // weight conversions (one fused launch) + wcat + eapad
    cvt_all<<<dim3(1664), blk, 0, stream>>>(
        le2w, geomw, downw, upw, linw, lin2w, o1w, wbuf);
    build_wcat<<<dim3(32), blk, 0, stream>>>(le1w, le12w, le1b, le12b, wb_cat, bcat);
    build_eapad<<<dim3((E * 8 + 255) / 256), blk, 0, stream>>>(
        rel_pos, edge_attr, eapad, E);

    // counting sort by dst
    hipMemsetAsync(cnt, 0, (size_t)N * sizeof(int), stream);
    edge_hist<<<dim3(3125), blk, 0, stream>>>(edst, cnt, E);
    scan_excl<<<dim3(1), dim3(1024), 0, stream>>>(cnt, N);
    edge_rank<<<dim3(3125), blk, 0, stream>>>(esrc, edst, cnt, rank, src_s, dsts, E);

    // fused edge embedding (permuted into dst-sorted order)
    edge_embed_fused<<<dim3(mbE), blk, 0, stream>>>(
        eapad, wb_cat, bcat, wb_le2, le2b, rank, ebf, E);

    // node embedding: hb0 -> t1 -> h  (hb0 aliases eapad region; edge_embed done)
    node_gather<<<dim3((N + 3) / 4), blk, 0, stream>>>(z, tag, embw, tembw, hb0, N);
    mgemm<256, A_F32, ME_STORE_F32, false><<<dim3(mbN, 2), blk, 0, stream>>>(
        hb0, wb_lin, linb, t1, nullptr, N, 256, nullptr);
    mgemm<256, A_F32, ME_STORE_F32, false><<<dim3(mbN, 2), blk, 0, stream>>>(
        t1, wb_lin2, lin2b, h, nullptr, N, 256, nullptr);

    // interaction blocks
    for (int l = 0; l < 3; ++l) {
        mgemm<256, A_F32, ME_STORE_BF16, false><<<dim3(mbN, 1), blk, 0, stream>>>(
            h, wb_down + (size_t)l * 32768, downb + (size_t)l * 128,
            nullptr, hdb, N, 128, nullptr);
        hipMemsetAsync(agg, 0, (size_t)N * 128 * sizeof(float), stream);
        msg_agg<<<dim3(mbE), blk, 0, stream>>>(
            ebf, wb_geom + (size_t)l * 16384, geomb + (size_t)l * 128,
            (const unsigned int*)hdb, src_s, dsts, agg, E);
        hipMemsetAsync(stats, 0, 256 * sizeof(float), stream);
        gn_stats<<<dim3(256), blk, 0, stream>>>(agg, stats, N);
        gn_finalize<<<dim3(1), dim3(128), 0, stream>>>(
            stats, gnw + (size_t)l * 128, gnb + (size_t)l * 128,
            gnms + (size_t)l * 128, ab, 1.0f / (float)N);
        gn_apply<<<dim3(512), blk, 0, stream>>>(agg, ab, (unsigned int*)ga, N * 64);
        mgemm<128, A_BF16, ME_RESID, true><<<dim3(mbN, 2), blk, 0, stream>>>(
            ga, wb_up + (size_t)l * 32768, upb + (size_t)l * 256,
            h, nullptr, N, 256, nullptr);
    }

    // readout
    mgemm<256, A_F32, ME_STORE_F32, false><<<dim3(mbN, 1), blk, 0, stream>>>(
        h, wb_o1, o1b, h1, nullptr, N, 128, nullptr);
    hipMemsetAsync(d_out, 0, 32 * sizeof(float), stream);
    out_reduce<<<dim3(512), blk, 0, stream>>>(h1, o2w, o2b, batch, (float*)d_out, N);
}

// Round 8
// 1642.482 us; speedup vs baseline: 1.3338x; 1.3338x over previous
//
#include <hip/hip_runtime.h>
#include <math.h>

// FAENet forward. All GEMMs via bf16 MFMA (16x16x32), fp32 accumulate.
// KEY LAYOUT TRICK (r3): mfma operands SWAPPED -> mfma(W_frag, A_frag, acc).
// Lane holds 1 output row x 4 CONSECUTIVE cols -> vectorized epilogues.
// r7: REVERT r6's msg_agg fusion (serial segment scan killed TLP; -350us).
// Back to geom-GEMM + csr_gather. NEW mgemm_bs for A_BF16 K=128 GEMMs
// (geom, up): stage the 128x128 bf16 A tile into LDS via 8x16B coalesced
// loads/thread (reg->ds_write, XOR chunk swizzle vs stride-256B conflicts).
// Rationale: geom was MLP-limited (~16 loads/wave in flight -> 1.87 TB/s by
// Little's law); staging puts 32KB/block in flight. sOut aliases the A tile
// in the bf16 epilogue (LDS stays 32KB -> 5 blocks/CU).
// r4: build_eapad pre-pass -> edge stage-1 A loads direct from global.
// out_reduce: contiguous per-wave chunks over sorted batch (~2K atomics).
// silu: v_rcp_f32 instead of IEEE divide (~1ulp; bf16 output absorbs it).

#define EPS_GN 1e-5f

typedef __attribute__((ext_vector_type(8))) short bf16x8;
typedef __attribute__((ext_vector_type(4))) float f32x4;

__device__ __forceinline__ float silu_f(float x) {
    float e = __expf(-x);
    return x * __builtin_amdgcn_rcpf(1.0f + e);
}
__device__ __forceinline__ float bf2f(unsigned int u) {
    union { unsigned int i; float f; } c;
    c.i = u << 16;
    return c.f;
}
__device__ __forceinline__ unsigned int f2bf(float x) {
    union { float f; unsigned int i; } c;
    c.f = x;
    unsigned int r = c.i + 0x7fffu + ((c.i >> 16) & 1u);
    return r >> 16;
}

enum { A_BF16 = 0, A_F32 = 1 };
enum { ME_STORE_F32 = 0, ME_STORE_BF16 = 1, ME_PERM_BF16 = 2, ME_RESID = 3 };

// C[M x NFTOT] = epi(A[M x K] @ W[NFTOT x K]^T + bias), MFMA bf16.
// acc[tm][tn] layout (operand-swapped): lane row = 16*tm + l16,
// cols = 16*tn + quad*4 + rg (4 consecutive features per lane).
// NOTE: ME_STORE_BF16 / ME_PERM_BF16 require NFTOT==128 and gridDim.y==1.
template<int K, int AMODE, int EPI, bool PRELW>
__global__ __launch_bounds__(256)
void mgemm(const void* __restrict__ Ap, const unsigned short* __restrict__ Wp,
           const float* __restrict__ bias, float* __restrict__ Cf,
           unsigned short* __restrict__ Cb, int M, int NFTOT,
           const int* __restrict__ perm)
{
    constexpr int KS = K / 32;
    const int tid = threadIdx.x;
    const int lane = tid & 63;
    const int wv = tid >> 6;                    // 0..3
    const int l16 = lane & 15;
    const int quad = lane >> 4;                 // 0..3
    const int m0 = blockIdx.x * 128 + (wv >> 1) * 64;
    const int n0 = blockIdx.y * 128 + (wv & 1) * 64;

    bf16x8 wpre[PRELW ? (KS * 4) : 1];
    if (PRELW) {
#pragma unroll
        for (int t = 0; t < 4; ++t)
#pragma unroll
            for (int s = 0; s < KS; ++s)
                wpre[t * KS + s] = *(const bf16x8*)(Wp +
                    (size_t)(n0 + 16 * t + l16) * K + s * 32 + quad * 8);
    }

    f32x4 acc[4][4];
#pragma unroll
    for (int i = 0; i < 4; ++i)
#pragma unroll
        for (int j = 0; j < 4; ++j) acc[i][j] = (f32x4){0.f, 0.f, 0.f, 0.f};

    for (int s = 0; s < KS; ++s) {
        bf16x8 af[4];
#pragma unroll
        for (int t = 0; t < 4; ++t) {
            int r = m0 + 16 * t + l16;
            if (r >= M) r = M - 1;
            if (AMODE == A_BF16) {
                af[t] = *(const bf16x8*)((const unsigned short*)Ap +
                                         (size_t)r * K + s * 32 + quad * 8);
            } else {
                const float* ap = (const float*)Ap + (size_t)r * K + s * 32 + quad * 8;
                float4 x0 = *(const float4*)ap;
                float4 x1 = *(const float4*)(ap + 4);
                bf16x8 v;
                v[0] = (short)f2bf(x0.x); v[1] = (short)f2bf(x0.y);
                v[2] = (short)f2bf(x0.z); v[3] = (short)f2bf(x0.w);
                v[4] = (short)f2bf(x1.x); v[5] = (short)f2bf(x1.y);
                v[6] = (short)f2bf(x1.z); v[7] = (short)f2bf(x1.w);
                af[t] = v;
            }
        }
        bf16x8 wf[4];
#pragma unroll
        for (int t = 0; t < 4; ++t) {
            if (PRELW) wf[t] = wpre[t * KS + s];
            else       wf[t] = *(const bf16x8*)(Wp +
                           (size_t)(n0 + 16 * t + l16) * K + s * 32 + quad * 8);
        }
#pragma unroll
        for (int tm = 0; tm < 4; ++tm)
#pragma unroll
            for (int tn = 0; tn < 4; ++tn)
                acc[tm][tn] = __builtin_amdgcn_mfma_f32_16x16x32_bf16(
                    wf[tn], af[tm], acc[tm][tn], 0, 0, 0);
    }

    if constexpr (EPI == ME_STORE_BF16 || EPI == ME_PERM_BF16) {
        // silu -> LDS (quad-XOR swizzle, b64 writes) -> cooperative row
        // store: each wave stores 32 full 256B rows, 16B/lane, full 64B lines.
        __shared__ unsigned short sOut[128 * 128];
        const int mwl = (wv >> 1) * 64;
        const int nwl = (wv & 1) * 64;
        const int key = (l16 >> 2) & 3;   // == (local_row>>2)&3
#pragma unroll
        for (int tn = 0; tn < 4; ++tn) {
            int cb = nwl + 16 * tn + quad * 4;
            float4 bv = *(const float4*)(bias + cb);
            int cs = cb ^ (key << 4);
#pragma unroll
            for (int tm = 0; tm < 4; ++tm) {
                int r = mwl + 16 * tm + l16;
                ushort4 pk;
                pk.x = (unsigned short)f2bf(silu_f(acc[tm][tn][0] + bv.x));
                pk.y = (unsigned short)f2bf(silu_f(acc[tm][tn][1] + bv.y));
                pk.z = (unsigned short)f2bf(silu_f(acc[tm][tn][2] + bv.z));
                pk.w = (unsigned short)f2bf(silu_f(acc[tm][tn][3] + bv.w));
                *(ushort4*)(sOut + r * 128 + cs) = pk;
            }
        }
        __syncthreads();
#pragma unroll
        for (int rr = 0; rr < 8; ++rr) {
            int r = (wv << 5) + (rr << 2) + quad;
            int gr = blockIdx.x * 128 + r;
            if (gr >= M) continue;
            int cs = (l16 * 8) ^ (((r >> 2) & 3) << 4);
            bf16x8 v = *(const bf16x8*)(sOut + r * 128 + cs);
            int dr = (EPI == ME_PERM_BF16) ? perm[gr] : gr;
            *(bf16x8*)(Cb + (size_t)dr * 128 + l16 * 8) = v;
        }
    } else {
        // f32 path: 4 consecutive cols per lane -> float4 stores (full lines).
#pragma unroll
        for (int tn = 0; tn < 4; ++tn) {
            int cb = n0 + 16 * tn + quad * 4;
            float4 bv = *(const float4*)(bias + cb);
#pragma unroll
            for (int tm = 0; tm < 4; ++tm) {
                int r = m0 + 16 * tm + l16;
                if (r >= M) continue;
                float4 v;
                v.x = silu_f(acc[tm][tn][0] + bv.x);
                v.y = silu_f(acc[tm][tn][1] + bv.y);
                v.z = silu_f(acc[tm][tn][2] + bv.z);
                v.w = silu_f(acc[tm][tn][3] + bv.w);
                float* dst = Cf + (size_t)r * NFTOT + cb;
                if (EPI == ME_STORE_F32) {
                    *(float4*)dst = v;
                } else { // ME_RESID
                    float4 o = *(const float4*)dst;
                    o.x += v.x; o.y += v.y; o.z += v.z; o.w += v.w;
                    *(float4*)dst = o;
                }
            }
        }
    }
}

// A_BF16, K=128 GEMM with LDS-staged A tile (geom / up). The 128x128 bf16 A
// tile is staged via 8 coalesced 16B loads/thread -> XOR-swizzled ds_write
// (chunk ^= r&7 kills the stride-256B bank conflict). Puts 32KB/block in
// flight during staging (geom was MLP-limited at 1.87 TB/s with per-frag
// loads). W streams from L2 (no preload; adds in-flight loads, saves VGPR).
// EPI==ME_STORE_BF16 requires NFTOT==128, gridDim.y==1 (sOut aliases aT).
template<int EPI>
__global__ __launch_bounds__(256)
void mgemm_bs(const unsigned short* __restrict__ Ap,
              const unsigned short* __restrict__ Wp,
              const float* __restrict__ bias, float* __restrict__ Cf,
              unsigned short* __restrict__ Cb, int M, int NFTOT)
{
    __shared__ unsigned short aT[128 * 128];   // 32KB; reused as sOut in bf16 epi
    const int tid = threadIdx.x;
    const int lane = tid & 63;
    const int wv = tid >> 6;
    const int l16 = lane & 15;
    const int quad = lane >> 4;
    const int m0b = blockIdx.x * 128;
    const int mw = (wv >> 1) * 64;
    const int nw = (wv & 1) * 64;
    const int n0 = blockIdx.y * 128 + nw;

    // stage A tile: 16 rows per 256-thread step, 16B/thread, rows clamped
    bf16x8 st[8];
#pragma unroll
    for (int i = 0; i < 8; ++i) {
        int L = i * 256 + tid;
        int r = L >> 4, c = L & 15;
        int rg = m0b + r; if (rg >= M) rg = M - 1;
        st[i] = *(const bf16x8*)(Ap + (size_t)rg * 128 + c * 8);
    }
#pragma unroll
    for (int i = 0; i < 8; ++i) {
        int L = i * 256 + tid;
        int r = L >> 4, c = L & 15;
        *(bf16x8*)(aT + r * 128 + (c ^ (r & 7)) * 8) = st[i];
    }
    __syncthreads();

    f32x4 acc[4][4];
#pragma unroll
    for (int i = 0; i < 4; ++i)
#pragma unroll
        for (int j = 0; j < 4; ++j) acc[i][j] = (f32x4){0.f, 0.f, 0.f, 0.f};

#pragma unroll
    for (int s = 0; s < 4; ++s) {
        bf16x8 af[4], wf[4];
#pragma unroll
        for (int t = 0; t < 4; ++t) {
            int r = mw + 16 * t + l16;
            int ch = (4 * s + quad) ^ (r & 7);
            af[t] = *(const bf16x8*)(aT + r * 128 + ch * 8);
        }
#pragma unroll
        for (int t = 0; t < 4; ++t)
            wf[t] = *(const bf16x8*)(Wp +
                (size_t)(n0 + 16 * t + l16) * 128 + s * 32 + quad * 8);
#pragma unroll
        for (int tm = 0; tm < 4; ++tm)
#pragma unroll
            for (int tn = 0; tn < 4; ++tn)
                acc[tm][tn] = __builtin_amdgcn_mfma_f32_16x16x32_bf16(
                    wf[tn], af[tm], acc[tm][tn], 0, 0, 0);
    }

    if constexpr (EPI == ME_STORE_BF16) {
        __syncthreads();   // all waves done reading aT before reuse as sOut
        unsigned short* sOut = aT;
        const int key = (l16 >> 2) & 3;
#pragma unroll
        for (int tn = 0; tn < 4; ++tn) {
            int cb = nw + 16 * tn + quad * 4;
            float4 bv = *(const float4*)(bias + cb);
            int cs = cb ^ (key << 4);
#pragma unroll
            for (int tm = 0; tm < 4; ++tm) {
                int r = mw + 16 * tm + l16;
                ushort4 pk;
                pk.x = (unsigned short)f2bf(silu_f(acc[tm][tn][0] + bv.x));
                pk.y = (unsigned short)f2bf(silu_f(acc[tm][tn][1] + bv.y));
                pk.z = (unsigned short)f2bf(silu_f(acc[tm][tn][2] + bv.z));
                pk.w = (unsigned short)f2bf(silu_f(acc[tm][tn][3] + bv.w));
                *(ushort4*)(sOut + r * 128 + cs) = pk;
            }
        }
        __syncthreads();
#pragma unroll
        for (int rr = 0; rr < 8; ++rr) {
            int r = (wv << 5) + (rr << 2) + quad;
            int gr = m0b + r;
            if (gr >= M) continue;
            int cs = (l16 * 8) ^ (((r >> 2) & 3) << 4);
            bf16x8 v = *(const bf16x8*)(sOut + r * 128 + cs);
            *(bf16x8*)(Cb + (size_t)gr * 128 + l16 * 8) = v;
        }
    } else { // ME_RESID (f32, NFTOT wide)
#pragma unroll
        for (int tn = 0; tn < 4; ++tn) {
            int cb = n0 + 16 * tn + quad * 4;
            float4 bv = *(const float4*)(bias + cb);
#pragma unroll
            for (int tm = 0; tm < 4; ++tm) {
                int r = m0b + mw + 16 * tm + l16;
                if (r >= M) continue;
                float* dst = Cf + (size_t)r * NFTOT + cb;
                float4 o = *(const float4*)dst;
                o.x += silu_f(acc[tm][tn][0] + bv.x);
                o.y += silu_f(acc[tm][tn][1] + bv.y);
                o.z += silu_f(acc[tm][tn][2] + bv.z);
                o.w += silu_f(acc[tm][tn][3] + bv.w);
                *(float4*)dst = o;
            }
        }
    }
}

// Wcat[128 x 64] bf16 matching eapad layout [rp k=0..2 | ea k=3..52 | pad]:
// rows 0..63: le1w at cols 0..2; rows 64..127: le12w at cols 3..52; rest 0.
// bcat[128] = [le1b | le12b].
__global__ __launch_bounds__(256)
void build_wcat(const float* __restrict__ w1, const float* __restrict__ w12,
                const float* __restrict__ b1, const float* __restrict__ b12,
                unsigned short* __restrict__ wcat, float* __restrict__ bcat)
{
    int i = blockIdx.x * 256 + threadIdx.x;
    if (i < 8192) {
        int r = i >> 6, c = i & 63;
        float v = 0.f;
        if (r < 64) { if (c < 3) v = w1[r * 3 + c]; }
        else        { if (c >= 3 && c < 53) v = w12[(r - 64) * 50 + (c - 3)]; }
        wcat[i] = (unsigned short)f2bf(v);
    }
    if (i < 128) bcat[i] = (i < 64) ? b1[i] : b12[i - 64];
}

// eapad[e][0:64] = bf16([rp[e][0..2] | ea[e][0..49] | zeros]), one 16B store
// per thread (fully coalesced). Feeds stage-1 A loads directly from global.
__global__ __launch_bounds__(256)
void build_eapad(const float* __restrict__ rp, const float* __restrict__ ea,
                 unsigned short* __restrict__ out, int E)
{
    int g = blockIdx.x * 256 + threadIdx.x;     // 16B group index
    if (g >= E * 8) return;
    int e = g >> 3, sub = g & 7;
    bf16x8 v;
#pragma unroll
    for (int j = 0; j < 8; ++j) {
        int c = sub * 8 + j;
        float x = 0.f;
        if (c < 3)       x = rp[(size_t)e * 3 + c];
        else if (c < 53) x = ea[(size_t)e * 50 + (c - 3)];
        v[j] = (short)f2bf(x);
    }
    *(bf16x8*)(out + (size_t)g * 8) = v;
}

// Fused edge embedding: e[perm[r]] = silu(silu(eapad @ Wcat^T + bcat) @ W2^T + b2)
// Operand-swapped MFMA; stage-1 A direct from global; LDS = sT only (32KB).
__global__ __launch_bounds__(256)
void edge_embed_fused(const unsigned short* __restrict__ eapad,
                      const unsigned short* __restrict__ wcat,
                      const float* __restrict__ bcat,
                      const unsigned short* __restrict__ w2,
                      const float* __restrict__ b2,
                      const int* __restrict__ perm,
                      unsigned short* __restrict__ ebf, int E)
{
    __shared__ unsigned short sT[128 * 128];   // 32 KB t-tile
    const int tid = threadIdx.x;
    const int m0 = blockIdx.x * 128;

    const int lane = tid & 63;
    const int wv = tid >> 6;
    const int l16 = lane & 15, quad = lane >> 4;
    const int mw = (wv >> 1) * 64;
    const int nw = (wv & 1) * 64;

    // stage 1: t = silu(A @ Wcat^T + bcat), K=64; A fragments from global
    f32x4 acc[4][4];
#pragma unroll
    for (int i = 0; i < 4; ++i)
#pragma unroll
        for (int j = 0; j < 4; ++j) acc[i][j] = (f32x4){0.f, 0.f, 0.f, 0.f};
#pragma unroll
    for (int s = 0; s < 2; ++s) {
        bf16x8 af[4], wf[4];
#pragma unroll
        for (int t = 0; t < 4; ++t) {
            int r = m0 + mw + 16 * t + l16;
            if (r >= E) r = E - 1;
            af[t] = *(const bf16x8*)(eapad + (size_t)r * 64 + s * 32 + quad * 8);
        }
#pragma unroll
        for (int t = 0; t < 4; ++t)
            wf[t] = *(const bf16x8*)(wcat +
                (size_t)(nw + 16 * t + l16) * 64 + s * 32 + quad * 8);
#pragma unroll
        for (int tm = 0; tm < 4; ++tm)
#pragma unroll
            for (int tn = 0; tn < 4; ++tn)
                acc[tm][tn] = __builtin_amdgcn_mfma_f32_16x16x32_bf16(
                    wf[tn], af[tm], acc[tm][tn], 0, 0, 0);
    }

    // silu+bias -> sT with k-group rotation swizzle, b64 writes:
    // element (r,c) at sT[r*128 + (((c>>3)+r)&15)*8 + (c&7)]
#pragma unroll
    for (int tn = 0; tn < 4; ++tn) {
        int cb = nw + 16 * tn + quad * 4;
        float4 bv = *(const float4*)(bcat + cb);
#pragma unroll
        for (int tm = 0; tm < 4; ++tm) {
            int r = mw + 16 * tm + l16;
            int g = ((cb >> 3) + r) & 15;
            ushort4 pk;
            pk.x = (unsigned short)f2bf(silu_f(acc[tm][tn][0] + bv.x));
            pk.y = (unsigned short)f2bf(silu_f(acc[tm][tn][1] + bv.y));
            pk.z = (unsigned short)f2bf(silu_f(acc[tm][tn][2] + bv.z));
            pk.w = (unsigned short)f2bf(silu_f(acc[tm][tn][3] + bv.w));
            *(ushort4*)(sT + r * 128 + g * 8 + (cb & 7)) = pk;
        }
    }
    __syncthreads();

    // stage 2: e = silu(t @ W2^T + b2), K=128 (operand-swapped)
    f32x4 acc2[4][4];
#pragma unroll
    for (int i = 0; i < 4; ++i)
#pragma unroll
        for (int j = 0; j < 4; ++j) acc2[i][j] = (f32x4){0.f, 0.f, 0.f, 0.f};
#pragma unroll
    for (int s = 0; s < 4; ++s) {
        bf16x8 af[4], wf[4];
#pragma unroll
        for (int t = 0; t < 4; ++t) {
            int r = mw + 16 * t + l16;
            int g = (s * 4 + quad + r) & 15;
            af[t] = *(const bf16x8*)(sT + r * 128 + g * 8);
        }
#pragma unroll
        for (int t = 0; t < 4; ++t)
            wf[t] = *(const bf16x8*)(w2 +
                (size_t)(nw + 16 * t + l16) * 128 + s * 32 + quad * 8);
#pragma unroll
        for (int tm = 0; tm < 4; ++tm)
#pragma unroll
            for (int tn = 0; tn < 4; ++tn)
                acc2[tm][tn] = __builtin_amdgcn_mfma_f32_16x16x32_bf16(
                    wf[tn], af[tm], acc2[tm][tn], 0, 0, 0);
    }

    // epilogue: silu -> sT (quad-keyed XOR swizzle, b64 writes) ->
    // cooperative permuted row store (16B/lane, full 64B lines).
    __syncthreads();   // all waves done reading sT before overwrite
#pragma unroll
    for (int tn = 0; tn < 4; ++tn) {
        int cb = nw + 16 * tn + quad * 4;
        float4 bv = *(const float4*)(b2 + cb);
#pragma unroll
        for (int tm = 0; tm < 4; ++tm) {
            int r = mw + 16 * tm + l16;
            int cs = cb ^ (((r >> 2) & 3) << 4);
            ushort4 pk;
            pk.x = (unsigned short)f2bf(silu_f(acc2[tm][tn][0] + bv.x));
            pk.y = (unsigned short)f2bf(silu_f(acc2[tm][tn][1] + bv.y));
            pk.z = (unsigned short)f2bf(silu_f(acc2[tm][tn][2] + bv.z));
            pk.w = (unsigned short)f2bf(silu_f(acc2[tm][tn][3] + bv.w));
            *(ushort4*)(sT + r * 128 + cs) = pk;
        }
    }
    __syncthreads();
    // each wave stores 32 rows: quad picks row within group-of-4, l16 picks 16B chunk
#pragma unroll
    for (int rr = 0; rr < 8; ++rr) {
        int r = (wv << 5) + (rr << 2) + quad;
        int gr = m0 + r;
        if (gr >= E) continue;
        int cs = (l16 * 8) ^ (((r >> 2) & 3) << 4);
        bf16x8 v = *(const bf16x8*)(sT + r * 128 + cs);
        *(bf16x8*)(ebf + (size_t)perm[gr] * 128 + l16 * 8) = v;
    }
}

// hb0[n][0:224]=emb_w[z[n]], [224:256]=tag_emb_w[tag[n]]  (f32)
__global__ __launch_bounds__(256)
void node_gather(const int* __restrict__ z, const int* __restrict__ tag,
                 const float* __restrict__ embw, const float* __restrict__ tembw,
                 float* __restrict__ hb0, int N)
{
    int lane = threadIdx.x & 63;
    int n = blockIdx.x * 4 + (threadIdx.x >> 6);
    if (n >= N) return;
    int f = lane * 4;
    float4 v;
    if (f < 224) v = *(const float4*)(embw + (size_t)z[n] * 224 + f);
    else         v = *(const float4*)(tembw + (size_t)tag[n] * 32 + (f - 224));
    *(float4*)(hb0 + (size_t)n * 256 + f) = v;
}

// all bf16 weight conversions in one launch; dst ranges are contiguous in wbuf
__global__ __launch_bounds__(256)
void cvt_all(const float* __restrict__ le2, const float* __restrict__ geom,
             const float* __restrict__ down, const float* __restrict__ up,
             const float* __restrict__ lin, const float* __restrict__ lin2,
             const float* __restrict__ o1, unsigned short* __restrict__ dst)
{
    int i = blockIdx.x * 256 + threadIdx.x;
    if (i >= 425984) return;
    float v;
    if      (i <  16384) v = le2[i];
    else if (i <  65536) v = geom[i - 16384];
    else if (i < 163840) v = down[i - 65536];
    else if (i < 262144) v = up[i - 163840];
    else if (i < 327680) v = lin[i - 262144];
    else if (i < 393216) v = lin2[i - 327680];
    else                 v = o1[i - 393216];
    dst[i] = (unsigned short)f2bf(v);
}

// ---- counting sort by dst ----
__global__ __launch_bounds__(256)
void edge_hist(const int* __restrict__ dst, int* __restrict__ cnt, int E)
{
    for (int i = blockIdx.x * 256 + threadIdx.x; i < E; i += gridDim.x * 256)
        atomicAdd(&cnt[dst[i]], 1);
}

__global__ __launch_bounds__(1024)
void scan_excl(int* __restrict__ cnt, int N)
{
    __shared__ int sdata[1024];
    __shared__ int s_carry;
    int tid = threadIdx.x;
    if (tid == 0) s_carry = 0;
    __syncthreads();
    for (int base = 0; base < N; base += 1024) {
        int i = base + tid;
        int v = (i < N) ? cnt[i] : 0;
        sdata[tid] = v;
        __syncthreads();
        for (int off = 1; off < 1024; off <<= 1) {
            int t = (tid >= off) ? sdata[tid - off] : 0;
            __syncthreads();
            sdata[tid] += t;
            __syncthreads();
        }
        int excl = sdata[tid] - v + s_carry;
        if (i < N) cnt[i] = excl;
        int tot = sdata[1023];
        __syncthreads();
        if (tid == 0) s_carry += tot;
        __syncthreads();
    }
}

__global__ __launch_bounds__(256)
void edge_rank(const int* __restrict__ src, const int* __restrict__ dst,
               int* __restrict__ cursor, int* __restrict__ rank,
               int* __restrict__ src_s, int E)
{
    for (int i = blockIdx.x * 256 + threadIdx.x; i < E; i += gridDim.x * 256) {
        int d = dst[i];
        int p = atomicAdd(&cursor[d], 1);
        rank[i] = p;
        src_s[p] = src[i];
    }
}

// CSR segment-sum: one wave per node d; agg[d] = sum el[p]*hd[src_s[p]]
__global__ __launch_bounds__(256)
void csr_gather(const unsigned int* __restrict__ el2,
                const unsigned int* __restrict__ hd2,
                const int* __restrict__ src_s,
                const int* __restrict__ rowend,
                float* __restrict__ agg, int N)
{
    int lane = threadIdx.x & 63;
    int d = blockIdx.x * 4 + (threadIdx.x >> 6);
    if (d >= N) return;
    int start = (d == 0) ? 0 : rowend[d - 1];
    int end = rowend[d];
    float a0 = 0.f, a1 = 0.f;
    int p = start;
    for (; p + 1 < end; p += 2) {
        int s0 = src_s[p], s1 = src_s[p + 1];
        unsigned int e0 = el2[(size_t)p * 64 + lane];
        unsigned int h0 = hd2[(size_t)s0 * 64 + lane];
        unsigned int e1 = el2[(size_t)(p + 1) * 64 + lane];
        unsigned int h1 = hd2[(size_t)s1 * 64 + lane];
        a0 = fmaf(bf2f(e0 & 0xffffu), bf2f(h0 & 0xffffu), a0);
        a1 = fmaf(bf2f(e0 >> 16),     bf2f(h0 >> 16),     a1);
        a0 = fmaf(bf2f(e1 & 0xffffu), bf2f(h1 & 0xffffu), a0);
        a1 = fmaf(bf2f(e1 >> 16),     bf2f(h1 >> 16),     a1);
    }
    if (p < end) {
        int s0 = src_s[p];
        unsigned int e0 = el2[(size_t)p * 64 + lane];
        unsigned int h0 = hd2[(size_t)s0 * 64 + lane];
        a0 = fmaf(bf2f(e0 & 0xffffu), bf2f(h0 & 0xffffu), a0);
        a1 = fmaf(bf2f(e0 >> 16),     bf2f(h0 >> 16),     a1);
    }
    *(float2*)(agg + (size_t)d * 128 + 2 * lane) = make_float2(a0, a1);
}

__global__ __launch_bounds__(256)
void gn_stats(const float* __restrict__ agg, float* __restrict__ sums, int N)
{
    __shared__ float red[512];
    int f = threadIdx.x & 127;
    int sub = threadIdx.x >> 7;
    float s = 0.f, s2 = 0.f;
    for (int r = blockIdx.x * 2 + sub; r < N; r += gridDim.x * 2) {
        float v = agg[(size_t)r * 128 + f];
        s += v;
        s2 += v * v;
    }
    red[threadIdx.x] = s;
    red[256 + threadIdx.x] = s2;
    __syncthreads();
    if (sub == 0) {
        s = red[f] + red[128 + f];
        s2 = red[256 + f] + red[384 + f];
        atomicAdd(&sums[f], s);
        atomicAdd(&sums[128 + f], s2);
    }
}

__global__ void gn_finalize(const float* __restrict__ sums,
                            const float* __restrict__ gnw, const float* __restrict__ gnb,
                            const float* __restrict__ gnms, float* __restrict__ ab,
                            float invN)
{
    int f = threadIdx.x; // 128
    float mean = sums[f] * invN;
    float ex2 = sums[128 + f] * invN;
    float m2 = mean * gnms[f];
    float var = ex2 - 2.f * m2 * mean + m2 * m2;
    float rstd = 1.0f / sqrtf(var + EPS_GN);
    float a = gnw[f] * rstd;
    ab[f] = a;
    ab[128 + f] = gnb[f] - a * m2;
}

// ga = bf16(silu(a*agg+b)) elementwise
__global__ __launch_bounds__(256)
void gn_apply(const float* __restrict__ agg, const float* __restrict__ ab,
              unsigned int* __restrict__ ga, int n2 /* N*64 */)
{
    for (int i = blockIdx.x * 256 + threadIdx.x; i < n2; i += gridDim.x * 256) {
        int f = (i & 63) * 2;
        float2 v = *(const float2*)(agg + (size_t)i * 2);
        float r0 = silu_f(ab[f] * v.x + ab[128 + f]);
        float r1 = silu_f(ab[f + 1] * v.y + ab[129 + f]);
        ga[i] = f2bf(r0) | (f2bf(r1) << 16);
    }
}

// out[g] += per-graph sum of (h1[r].w2)+b2 over sorted batch, run-accumulated.
__global__ __launch_bounds__(256)
void out_reduce(const float* __restrict__ h1, const float* __restrict__ w2,
                const float* __restrict__ b2, const int* __restrict__ batch,
                float* __restrict__ out, int N)
{
    int lane = threadIdx.x & 63;
    int wid = blockIdx.x * 4 + (threadIdx.x >> 6);
    int nwaves = gridDim.x * 4;
    int chunk = (N + nwaves - 1) / nwaves;
    int r0 = wid * chunk;
    int r1 = r0 + chunk; if (r1 > N) r1 = N;
    if (r0 >= r1) return;
    float wa = w2[lane], wb = w2[64 + lane];
    float bb = b2[0];
    int cur = batch[r0];
    float acc = 0.f;
    int cnt = 0;
    for (int r = r0; r < r1; ++r) {
        int g = batch[r];
        if (g != cur) {
            float v = acc;
#pragma unroll
            for (int o = 32; o > 0; o >>= 1) v += __shfl_down(v, o);
            if (lane == 0) atomicAdd(&out[cur], v + (float)cnt * bb);
            cur = g; acc = 0.f; cnt = 0;
        }
        acc = fmaf(h1[(size_t)r * 128 + lane], wa, acc);
        acc = fmaf(h1[(size_t)r * 128 + 64 + lane], wb, acc);
        ++cnt;
    }
    float v = acc;
#pragma unroll
    for (int o = 32; o > 0; o >>= 1) v += __shfl_down(v, o);
    if (lane == 0) atomicAdd(&out[cur], v + (float)cnt * bb);
}

extern "C" void kernel_launch(void* const* d_in, const int* in_sizes, int n_in,
                              void* d_out, int out_size, void* d_ws, size_t ws_size,
                              hipStream_t stream)
{
    const int*   z         = (const int*)d_in[0];
    const int*   tag       = (const int*)d_in[1];
    const float* rel_pos   = (const float*)d_in[2];
    const float* edge_attr = (const float*)d_in[3];
    const int*   eidx      = (const int*)d_in[4];
    const int*   batch     = (const int*)d_in[5];
    const float* le1w  = (const float*)d_in[6];
    const float* le1b  = (const float*)d_in[7];
    const float* le12w = (const float*)d_in[8];
    const float* le12b = (const float*)d_in[9];
    const float* le2w  = (const float*)d_in[10];
    const float* le2b  = (const float*)d_in[11];
    const float* embw  = (const float*)d_in[12];
    const float* tembw = (const float*)d_in[13];
    const float* linw  = (const float*)d_in[14];
    const float* linb  = (const float*)d_in[15];
    const float* lin2w = (const float*)d_in[16];
    const float* lin2b = (const float*)d_in[17];
    const float* geomw = (const float*)d_in[18];
    const float* geomb = (const float*)d_in[19];
    const float* downw = (const float*)d_in[20];
    const float* downb = (const float*)d_in[21];
    const float* upw   = (const float*)d_in[22];
    const float* upb   = (const float*)d_in[23];
    const float* gnw   = (const float*)d_in[24];
    const float* gnb   = (const float*)d_in[25];
    const float* gnms  = (const float*)d_in[26];
    const float* o1w   = (const float*)d_in[27];
    const float* o1b   = (const float*)d_in[28];
    const float* o2w   = (const float*)d_in[29];
    const float* o2b   = (const float*)d_in[30];

    const int N = in_sizes[0];
    const int E = in_sizes[2] / 3;
    const int* esrc = eidx;
    const int* edst = eidx + E;

    char* ws = (char*)d_ws;
    size_t off = 0;
    unsigned short* T = (unsigned short*)(ws + off); off += (size_t)E * 128 * 2;   // hb0+t1 / el / eapad
    unsigned short* ebf = (unsigned short*)(ws + off); off += (size_t)E * 128 * 2;
    float* h   = (float*)(ws + off); off += (size_t)N * 256 * 4;
    float* agg = (float*)(ws + off); off += (size_t)N * 128 * 4;
    unsigned short* hdb = (unsigned short*)(ws + off); off += (size_t)N * 128 * 2;
    int*   cnt   = (int*)(ws + off); off += (size_t)N * 4;
    int*   src_s = (int*)(ws + off); off += (size_t)E * 4;
    unsigned short* wbuf = (unsigned short*)(ws + off); off += 442368ull * 2;
    float* stats = (float*)(ws + off); off += 256 * 4;
    float* ab    = (float*)(ws + off); off += 256 * 4;
    float* bcat  = (float*)(ws + off); off += 128;

    // aliases
    unsigned short* eapad = T;                      // E*64 bf16 (dead after edge_embed)
    float* hb0 = (float*)T;                         // N*256 f32 (after edge_embed)
    float* t1  = (float*)T + (size_t)N * 256;       // N*256 f32 (dead before layers)
    unsigned short* el = T;                         // E*128 bf16 (layers)
    int*   rank = (int*)agg;                        // E ints, dead before agg first write
    unsigned short* ga = hdb;                       // bf16 N*128, written after csr_gather
    float* h1 = agg;                                // N*128 f32, written after agg last read

    // bf16 weight buffer offsets
    unsigned short* wb_le2  = wbuf;                 // 16384
    unsigned short* wb_geom = wbuf + 16384;         // 3*16384
    unsigned short* wb_down = wbuf + 65536;         // 3*32768
    unsigned short* wb_up   = wbuf + 163840;        // 3*32768
    unsigned short* wb_lin  = wbuf + 262144;        // 65536
    unsigned short* wb_lin2 = wbuf + 327680;        // 65536
    unsigned short* wb_o1   = wbuf + 393216;        // 32768
    unsigned short* wb_cat  = wbuf + 425984;        // 8192

    const int mbE = (E + 127) / 128;
    const int mbN = (N + 127) / 128;
    dim3 blk(256);

    // weight conversions (one fused launch) + wcat + eapad
    cvt_all<<<dim3(1664), blk, 0, stream>>>(
        le2w, geomw, downw, upw, linw, lin2w, o1w, wbuf);
    build_wcat<<<dim3(32), blk, 0, stream>>>(le1w, le12w, le1b, le12b, wb_cat, bcat);
    build_eapad<<<dim3((E * 8 + 255) / 256), blk, 0, stream>>>(
        rel_pos, edge_attr, eapad, E);

    // counting sort by dst
    hipMemsetAsync(cnt, 0, (size_t)N * sizeof(int), stream);
    edge_hist<<<dim3(3125), blk, 0, stream>>>(edst, cnt, E);
    scan_excl<<<dim3(1), dim3(1024), 0, stream>>>(cnt, N);
    edge_rank<<<dim3(3125), blk, 0, stream>>>(esrc, edst, cnt, rank, src_s, E);

    // fused edge embedding (permuted into dst-sorted order)
    edge_embed_fused<<<dim3(mbE), blk, 0, stream>>>(
        eapad, wb_cat, bcat, wb_le2, le2b, rank, ebf, E);

    // node embedding: hb0 -> t1 -> h  (hb0 aliases eapad region; edge_embed done)
    node_gather<<<dim3((N + 3) / 4), blk, 0, stream>>>(z, tag, embw, tembw, hb0, N);
    mgemm<256, A_F32, ME_STORE_F32, false><<<dim3(mbN, 2), blk, 0, stream>>>(
        hb0, wb_lin, linb, t1, nullptr, N, 256, nullptr);
    mgemm<256, A_F32, ME_STORE_F32, false><<<dim3(mbN, 2), blk, 0, stream>>>(
        t1, wb_lin2, lin2b, h, nullptr, N, 256, nullptr);

    // interaction blocks
    for (int l = 0; l < 3; ++l) {
        mgemm<256, A_F32, ME_STORE_BF16, false><<<dim3(mbN, 1), blk, 0, stream>>>(
            h, wb_down + (size_t)l * 32768, downb + (size_t)l * 128,
            nullptr, hdb, N, 128, nullptr);
        mgemm_bs<ME_STORE_BF16><<<dim3(mbE, 1), blk, 0, stream>>>(
            ebf, wb_geom + (size_t)l * 16384, geomb + (size_t)l * 128,
            nullptr, el, E, 128);
        csr_gather<<<dim3((N + 3) / 4), blk, 0, stream>>>(
            (const unsigned int*)el, (const unsigned int*)hdb, src_s, cnt, agg, N);
        hipMemsetAsync(stats, 0, 256 * sizeof(float), stream);
        gn_stats<<<dim3(256), blk, 0, stream>>>(agg, stats, N);
        gn_finalize<<<dim3(1), dim3(128), 0, stream>>>(
            stats, gnw + (size_t)l * 128, gnb + (size_t)l * 128,
            gnms + (size_t)l * 128, ab, 1.0f / (float)N);
        gn_apply<<<dim3(512), blk, 0, stream>>>(agg, ab, (unsigned int*)ga, N * 64);
        mgemm_bs<ME_RESID><<<dim3(mbN, 2), blk, 0, stream>>>(
            ga, wb_up + (size_t)l * 32768, upb + (size_t)l * 256,
            h, nullptr, N, 256);
    }

    // readout
    mgemm<256, A_F32, ME_STORE_F32, false><<<dim3(mbN, 1), blk, 0, stream>>>(
        h, wb_o1, o1b, h1, nullptr, N, 128, nullptr);
    hipMemsetAsync(d_out, 0, 32 * sizeof(float), stream);
    out_reduce<<<dim3(512), blk, 0, stream>>>(h1, o2w, o2b, batch, (float*)d_out, N);
}

// Round 9
// 1570.904 us; speedup vs baseline: 1.3946x; 1.0456x over previous
//
#include <hip/hip_runtime.h>
#include <math.h>

// FAENet forward. All GEMMs via bf16 MFMA (16x16x32), fp32 accumulate.
// KEY LAYOUT TRICK (r3): mfma operands SWAPPED -> mfma(W_frag, A_frag, acc).
// Lane holds 1 output row x 4 CONSECUTIVE cols -> vectorized epilogues.
// r8: activations stored bf16 end-to-end where numerically identical
// (we always rounded A to bf16 in-register before MFMA anyway):
// node_gather emits bf16; lin reads A_BF16, writes bf16 t1 (generalized
// LDS epilogue: row stride NFTOT, col base by*128); lin2 reads A_BF16.
// csr_gather unrolled 4x (8 outstanding 256B loads/wave, MLP lever).
// r7: mgemm_bs for A_BF16 K=128 GEMMs (geom, up): LDS-staged A tile.
// r4: build_eapad pre-pass -> edge stage-1 A loads direct from global.
// out_reduce: contiguous per-wave chunks over sorted batch (~2K atomics).
// silu: v_rcp_f32 instead of IEEE divide (~1ulp; bf16 output absorbs it).

#define EPS_GN 1e-5f

typedef __attribute__((ext_vector_type(8))) short bf16x8;
typedef __attribute__((ext_vector_type(4))) float f32x4;

__device__ __forceinline__ float silu_f(float x) {
    float e = __expf(-x);
    return x * __builtin_amdgcn_rcpf(1.0f + e);
}
__device__ __forceinline__ float bf2f(unsigned int u) {
    union { unsigned int i; float f; } c;
    c.i = u << 16;
    return c.f;
}
__device__ __forceinline__ unsigned int f2bf(float x) {
    union { float f; unsigned int i; } c;
    c.f = x;
    unsigned int r = c.i + 0x7fffu + ((c.i >> 16) & 1u);
    return r >> 16;
}

enum { A_BF16 = 0, A_F32 = 1 };
enum { ME_STORE_F32 = 0, ME_STORE_BF16 = 1, ME_PERM_BF16 = 2, ME_RESID = 3 };

// C[M x NFTOT] = epi(A[M x K] @ W[NFTOT x K]^T + bias), MFMA bf16.
// acc[tm][tn] layout (operand-swapped): lane row = 16*tm + l16,
// cols = 16*tn + quad*4 + rg (4 consecutive features per lane).
// bf16 epilogue: NFTOT multiple of 128; each (bx,by) block stores 128 rows
// x 128-col half at col base by*128 (full 256B contiguous segments).
// ME_PERM_BF16 additionally requires NFTOT==128 (perm indexes full rows).
template<int K, int AMODE, int EPI, bool PRELW>
__global__ __launch_bounds__(256)
void mgemm(const void* __restrict__ Ap, const unsigned short* __restrict__ Wp,
           const float* __restrict__ bias, float* __restrict__ Cf,
           unsigned short* __restrict__ Cb, int M, int NFTOT,
           const int* __restrict__ perm)
{
    constexpr int KS = K / 32;
    const int tid = threadIdx.x;
    const int lane = tid & 63;
    const int wv = tid >> 6;                    // 0..3
    const int l16 = lane & 15;
    const int quad = lane >> 4;                 // 0..3
    const int m0 = blockIdx.x * 128 + (wv >> 1) * 64;
    const int n0 = blockIdx.y * 128 + (wv & 1) * 64;

    bf16x8 wpre[PRELW ? (KS * 4) : 1];
    if (PRELW) {
#pragma unroll
        for (int t = 0; t < 4; ++t)
#pragma unroll
            for (int s = 0; s < KS; ++s)
                wpre[t * KS + s] = *(const bf16x8*)(Wp +
                    (size_t)(n0 + 16 * t + l16) * K + s * 32 + quad * 8);
    }

    f32x4 acc[4][4];
#pragma unroll
    for (int i = 0; i < 4; ++i)
#pragma unroll
        for (int j = 0; j < 4; ++j) acc[i][j] = (f32x4){0.f, 0.f, 0.f, 0.f};

    for (int s = 0; s < KS; ++s) {
        bf16x8 af[4];
#pragma unroll
        for (int t = 0; t < 4; ++t) {
            int r = m0 + 16 * t + l16;
            if (r >= M) r = M - 1;
            if (AMODE == A_BF16) {
                af[t] = *(const bf16x8*)((const unsigned short*)Ap +
                                         (size_t)r * K + s * 32 + quad * 8);
            } else {
                const float* ap = (const float*)Ap + (size_t)r * K + s * 32 + quad * 8;
                float4 x0 = *(const float4*)ap;
                float4 x1 = *(const float4*)(ap + 4);
                bf16x8 v;
                v[0] = (short)f2bf(x0.x); v[1] = (short)f2bf(x0.y);
                v[2] = (short)f2bf(x0.z); v[3] = (short)f2bf(x0.w);
                v[4] = (short)f2bf(x1.x); v[5] = (short)f2bf(x1.y);
                v[6] = (short)f2bf(x1.z); v[7] = (short)f2bf(x1.w);
                af[t] = v;
            }
        }
        bf16x8 wf[4];
#pragma unroll
        for (int t = 0; t < 4; ++t) {
            if (PRELW) wf[t] = wpre[t * KS + s];
            else       wf[t] = *(const bf16x8*)(Wp +
                           (size_t)(n0 + 16 * t + l16) * K + s * 32 + quad * 8);
        }
#pragma unroll
        for (int tm = 0; tm < 4; ++tm)
#pragma unroll
            for (int tn = 0; tn < 4; ++tn)
                acc[tm][tn] = __builtin_amdgcn_mfma_f32_16x16x32_bf16(
                    wf[tn], af[tm], acc[tm][tn], 0, 0, 0);
    }

    if constexpr (EPI == ME_STORE_BF16 || EPI == ME_PERM_BF16) {
        // silu -> LDS (quad-XOR swizzle, b64 writes) -> cooperative row
        // store: each wave stores 32 x 256B row-halves, 16B/lane, full lines.
        __shared__ unsigned short sOut[128 * 128];
        const int mwl = (wv >> 1) * 64;
        const int nwl = (wv & 1) * 64;
        const int cbase = blockIdx.y * 128;
        const int key = (l16 >> 2) & 3;   // == (local_row>>2)&3
#pragma unroll
        for (int tn = 0; tn < 4; ++tn) {
            int cb = nwl + 16 * tn + quad * 4;
            float4 bv = *(const float4*)(bias + cbase + cb);
            int cs = cb ^ (key << 4);
#pragma unroll
            for (int tm = 0; tm < 4; ++tm) {
                int r = mwl + 16 * tm + l16;
                ushort4 pk;
                pk.x = (unsigned short)f2bf(silu_f(acc[tm][tn][0] + bv.x));
                pk.y = (unsigned short)f2bf(silu_f(acc[tm][tn][1] + bv.y));
                pk.z = (unsigned short)f2bf(silu_f(acc[tm][tn][2] + bv.z));
                pk.w = (unsigned short)f2bf(silu_f(acc[tm][tn][3] + bv.w));
                *(ushort4*)(sOut + r * 128 + cs) = pk;
            }
        }
        __syncthreads();
#pragma unroll
        for (int rr = 0; rr < 8; ++rr) {
            int r = (wv << 5) + (rr << 2) + quad;
            int gr = blockIdx.x * 128 + r;
            if (gr >= M) continue;
            int cs = (l16 * 8) ^ (((r >> 2) & 3) << 4);
            bf16x8 v = *(const bf16x8*)(sOut + r * 128 + cs);
            int dr = (EPI == ME_PERM_BF16) ? perm[gr] : gr;
            *(bf16x8*)(Cb + (size_t)dr * NFTOT + cbase + l16 * 8) = v;
        }
    } else {
        // f32 path: 4 consecutive cols per lane -> float4 stores (full lines).
#pragma unroll
        for (int tn = 0; tn < 4; ++tn) {
            int cb = n0 + 16 * tn + quad * 4;
            float4 bv = *(const float4*)(bias + cb);
#pragma unroll
            for (int tm = 0; tm < 4; ++tm) {
                int r = m0 + 16 * tm + l16;
                if (r >= M) continue;
                float4 v;
                v.x = silu_f(acc[tm][tn][0] + bv.x);
                v.y = silu_f(acc[tm][tn][1] + bv.y);
                v.z = silu_f(acc[tm][tn][2] + bv.z);
                v.w = silu_f(acc[tm][tn][3] + bv.w);
                float* dst = Cf + (size_t)r * NFTOT + cb;
                if (EPI == ME_STORE_F32) {
                    *(float4*)dst = v;
                } else { // ME_RESID
                    float4 o = *(const float4*)dst;
                    o.x += v.x; o.y += v.y; o.z += v.z; o.w += v.w;
                    *(float4*)dst = o;
                }
            }
        }
    }
}

// A_BF16, K=128 GEMM with LDS-staged A tile (geom / up). The 128x128 bf16 A
// tile is staged via 8 coalesced 16B loads/thread -> XOR-swizzled ds_write
// (chunk ^= r&7 kills the stride-256B bank conflict). Puts 32KB/block in
// flight during staging (geom was MLP-limited at 1.87 TB/s with per-frag
// loads). W streams from L2 (no preload; adds in-flight loads, saves VGPR).
// EPI==ME_STORE_BF16 requires NFTOT==128, gridDim.y==1 (sOut aliases aT).
template<int EPI>
__global__ __launch_bounds__(256)
void mgemm_bs(const unsigned short* __restrict__ Ap,
              const unsigned short* __restrict__ Wp,
              const float* __restrict__ bias, float* __restrict__ Cf,
              unsigned short* __restrict__ Cb, int M, int NFTOT)
{
    __shared__ unsigned short aT[128 * 128];   // 32KB; reused as sOut in bf16 epi
    const int tid = threadIdx.x;
    const int lane = tid & 63;
    const int wv = tid >> 6;
    const int l16 = lane & 15;
    const int quad = lane >> 4;
    const int m0b = blockIdx.x * 128;
    const int mw = (wv >> 1) * 64;
    const int nw = (wv & 1) * 64;
    const int n0 = blockIdx.y * 128 + nw;

    // stage A tile: 16 rows per 256-thread step, 16B/thread, rows clamped
    bf16x8 st[8];
#pragma unroll
    for (int i = 0; i < 8; ++i) {
        int L = i * 256 + tid;
        int r = L >> 4, c = L & 15;
        int rg = m0b + r; if (rg >= M) rg = M - 1;
        st[i] = *(const bf16x8*)(Ap + (size_t)rg * 128 + c * 8);
    }
#pragma unroll
    for (int i = 0; i < 8; ++i) {
        int L = i * 256 + tid;
        int r = L >> 4, c = L & 15;
        *(bf16x8*)(aT + r * 128 + (c ^ (r & 7)) * 8) = st[i];
    }
    __syncthreads();

    f32x4 acc[4][4];
#pragma unroll
    for (int i = 0; i < 4; ++i)
#pragma unroll
        for (int j = 0; j < 4; ++j) acc[i][j] = (f32x4){0.f, 0.f, 0.f, 0.f};

#pragma unroll
    for (int s = 0; s < 4; ++s) {
        bf16x8 af[4], wf[4];
#pragma unroll
        for (int t = 0; t < 4; ++t) {
            int r = mw + 16 * t + l16;
            int ch = (4 * s + quad) ^ (r & 7);
            af[t] = *(const bf16x8*)(aT + r * 128 + ch * 8);
        }
#pragma unroll
        for (int t = 0; t < 4; ++t)
            wf[t] = *(const bf16x8*)(Wp +
                (size_t)(n0 + 16 * t + l16) * 128 + s * 32 + quad * 8);
#pragma unroll
        for (int tm = 0; tm < 4; ++tm)
#pragma unroll
            for (int tn = 0; tn < 4; ++tn)
                acc[tm][tn] = __builtin_amdgcn_mfma_f32_16x16x32_bf16(
                    wf[tn], af[tm], acc[tm][tn], 0, 0, 0);
    }

    if constexpr (EPI == ME_STORE_BF16) {
        __syncthreads();   // all waves done reading aT before reuse as sOut
        unsigned short* sOut = aT;
        const int key = (l16 >> 2) & 3;
#pragma unroll
        for (int tn = 0; tn < 4; ++tn) {
            int cb = nw + 16 * tn + quad * 4;
            float4 bv = *(const float4*)(bias + cb);
            int cs = cb ^ (key << 4);
#pragma unroll
            for (int tm = 0; tm < 4; ++tm) {
                int r = mw + 16 * tm + l16;
                ushort4 pk;
                pk.x = (unsigned short)f2bf(silu_f(acc[tm][tn][0] + bv.x));
                pk.y = (unsigned short)f2bf(silu_f(acc[tm][tn][1] + bv.y));
                pk.z = (unsigned short)f2bf(silu_f(acc[tm][tn][2] + bv.z));
                pk.w = (unsigned short)f2bf(silu_f(acc[tm][tn][3] + bv.w));
                *(ushort4*)(sOut + r * 128 + cs) = pk;
            }
        }
        __syncthreads();
#pragma unroll
        for (int rr = 0; rr < 8; ++rr) {
            int r = (wv << 5) + (rr << 2) + quad;
            int gr = m0b + r;
            if (gr >= M) continue;
            int cs = (l16 * 8) ^ (((r >> 2) & 3) << 4);
            bf16x8 v = *(const bf16x8*)(sOut + r * 128 + cs);
            *(bf16x8*)(Cb + (size_t)gr * 128 + l16 * 8) = v;
        }
    } else { // ME_RESID (f32, NFTOT wide)
#pragma unroll
        for (int tn = 0; tn < 4; ++tn) {
            int cb = n0 + 16 * tn + quad * 4;
            float4 bv = *(const float4*)(bias + cb);
#pragma unroll
            for (int tm = 0; tm < 4; ++tm) {
                int r = m0b + mw + 16 * tm + l16;
                if (r >= M) continue;
                float* dst = Cf + (size_t)r * NFTOT + cb;
                float4 o = *(const float4*)dst;
                o.x += silu_f(acc[tm][tn][0] + bv.x);
                o.y += silu_f(acc[tm][tn][1] + bv.y);
                o.z += silu_f(acc[tm][tn][2] + bv.z);
                o.w += silu_f(acc[tm][tn][3] + bv.w);
                *(float4*)dst = o;
            }
        }
    }
}

// Wcat[128 x 64] bf16 matching eapad layout [rp k=0..2 | ea k=3..52 | pad]:
// rows 0..63: le1w at cols 0..2; rows 64..127: le12w at cols 3..52; rest 0.
// bcat[128] = [le1b | le12b].
__global__ __launch_bounds__(256)
void build_wcat(const float* __restrict__ w1, const float* __restrict__ w12,
                const float* __restrict__ b1, const float* __restrict__ b12,
                unsigned short* __restrict__ wcat, float* __restrict__ bcat)
{
    int i = blockIdx.x * 256 + threadIdx.x;
    if (i < 8192) {
        int r = i >> 6, c = i & 63;
        float v = 0.f;
        if (r < 64) { if (c < 3) v = w1[r * 3 + c]; }
        else        { if (c >= 3 && c < 53) v = w12[(r - 64) * 50 + (c - 3)]; }
        wcat[i] = (unsigned short)f2bf(v);
    }
    if (i < 128) bcat[i] = (i < 64) ? b1[i] : b12[i - 64];
}

// eapad[e][0:64] = bf16([rp[e][0..2] | ea[e][0..49] | zeros]), one 16B store
// per thread (fully coalesced). Feeds stage-1 A loads directly from global.
__global__ __launch_bounds__(256)
void build_eapad(const float* __restrict__ rp, const float* __restrict__ ea,
                 unsigned short* __restrict__ out, int E)
{
    int g = blockIdx.x * 256 + threadIdx.x;     // 16B group index
    if (g >= E * 8) return;
    int e = g >> 3, sub = g & 7;
    bf16x8 v;
#pragma unroll
    for (int j = 0; j < 8; ++j) {
        int c = sub * 8 + j;
        float x = 0.f;
        if (c < 3)       x = rp[(size_t)e * 3 + c];
        else if (c < 53) x = ea[(size_t)e * 50 + (c - 3)];
        v[j] = (short)f2bf(x);
    }
    *(bf16x8*)(out + (size_t)g * 8) = v;
}

// Fused edge embedding: e[perm[r]] = silu(silu(eapad @ Wcat^T + bcat) @ W2^T + b2)
// Operand-swapped MFMA; stage-1 A direct from global; LDS = sT only (32KB).
__global__ __launch_bounds__(256)
void edge_embed_fused(const unsigned short* __restrict__ eapad,
                      const unsigned short* __restrict__ wcat,
                      const float* __restrict__ bcat,
                      const unsigned short* __restrict__ w2,
                      const float* __restrict__ b2,
                      const int* __restrict__ perm,
                      unsigned short* __restrict__ ebf, int E)
{
    __shared__ unsigned short sT[128 * 128];   // 32 KB t-tile
    const int tid = threadIdx.x;
    const int m0 = blockIdx.x * 128;

    const int lane = tid & 63;
    const int wv = tid >> 6;
    const int l16 = lane & 15, quad = lane >> 4;
    const int mw = (wv >> 1) * 64;
    const int nw = (wv & 1) * 64;

    // stage 1: t = silu(A @ Wcat^T + bcat), K=64; A fragments from global
    f32x4 acc[4][4];
#pragma unroll
    for (int i = 0; i < 4; ++i)
#pragma unroll
        for (int j = 0; j < 4; ++j) acc[i][j] = (f32x4){0.f, 0.f, 0.f, 0.f};
#pragma unroll
    for (int s = 0; s < 2; ++s) {
        bf16x8 af[4], wf[4];
#pragma unroll
        for (int t = 0; t < 4; ++t) {
            int r = m0 + mw + 16 * t + l16;
            if (r >= E) r = E - 1;
            af[t] = *(const bf16x8*)(eapad + (size_t)r * 64 + s * 32 + quad * 8);
        }
#pragma unroll
        for (int t = 0; t < 4; ++t)
            wf[t] = *(const bf16x8*)(wcat +
                (size_t)(nw + 16 * t + l16) * 64 + s * 32 + quad * 8);
#pragma unroll
        for (int tm = 0; tm < 4; ++tm)
#pragma unroll
            for (int tn = 0; tn < 4; ++tn)
                acc[tm][tn] = __builtin_amdgcn_mfma_f32_16x16x32_bf16(
                    wf[tn], af[tm], acc[tm][tn], 0, 0, 0);
    }

    // silu+bias -> sT with k-group rotation swizzle, b64 writes:
    // element (r,c) at sT[r*128 + (((c>>3)+r)&15)*8 + (c&7)]
#pragma unroll
    for (int tn = 0; tn < 4; ++tn) {
        int cb = nw + 16 * tn + quad * 4;
        float4 bv = *(const float4*)(bcat + cb);
#pragma unroll
        for (int tm = 0; tm < 4; ++tm) {
            int r = mw + 16 * tm + l16;
            int g = ((cb >> 3) + r) & 15;
            ushort4 pk;
            pk.x = (unsigned short)f2bf(silu_f(acc[tm][tn][0] + bv.x));
            pk.y = (unsigned short)f2bf(silu_f(acc[tm][tn][1] + bv.y));
            pk.z = (unsigned short)f2bf(silu_f(acc[tm][tn][2] + bv.z));
            pk.w = (unsigned short)f2bf(silu_f(acc[tm][tn][3] + bv.w));
            *(ushort4*)(sT + r * 128 + g * 8 + (cb & 7)) = pk;
        }
    }
    __syncthreads();

    // stage 2: e = silu(t @ W2^T + b2), K=128 (operand-swapped)
    f32x4 acc2[4][4];
#pragma unroll
    for (int i = 0; i < 4; ++i)
#pragma unroll
        for (int j = 0; j < 4; ++j) acc2[i][j] = (f32x4){0.f, 0.f, 0.f, 0.f};
#pragma unroll
    for (int s = 0; s < 4; ++s) {
        bf16x8 af[4], wf[4];
#pragma unroll
        for (int t = 0; t < 4; ++t) {
            int r = mw + 16 * t + l16;
            int g = (s * 4 + quad + r) & 15;
            af[t] = *(const bf16x8*)(sT + r * 128 + g * 8);
        }
#pragma unroll
        for (int t = 0; t < 4; ++t)
            wf[t] = *(const bf16x8*)(w2 +
                (size_t)(nw + 16 * t + l16) * 128 + s * 32 + quad * 8);
#pragma unroll
        for (int tm = 0; tm < 4; ++tm)
#pragma unroll
            for (int tn = 0; tn < 4; ++tn)
                acc2[tm][tn] = __builtin_amdgcn_mfma_f32_16x16x32_bf16(
                    wf[tn], af[tm], acc2[tm][tn], 0, 0, 0);
    }

    // epilogue: silu -> sT (quad-keyed XOR swizzle, b64 writes) ->
    // cooperative permuted row store (16B/lane, full 64B lines).
    __syncthreads();   // all waves done reading sT before overwrite
#pragma unroll
    for (int tn = 0; tn < 4; ++tn) {
        int cb = nw + 16 * tn + quad * 4;
        float4 bv = *(const float4*)(b2 + cb);
#pragma unroll
        for (int tm = 0; tm < 4; ++tm) {
            int r = mw + 16 * tm + l16;
            int cs = cb ^ (((r >> 2) & 3) << 4);
            ushort4 pk;
            pk.x = (unsigned short)f2bf(silu_f(acc2[tm][tn][0] + bv.x));
            pk.y = (unsigned short)f2bf(silu_f(acc2[tm][tn][1] + bv.y));
            pk.z = (unsigned short)f2bf(silu_f(acc2[tm][tn][2] + bv.z));
            pk.w = (unsigned short)f2bf(silu_f(acc2[tm][tn][3] + bv.w));
            *(ushort4*)(sT + r * 128 + cs) = pk;
        }
    }
    __syncthreads();
    // each wave stores 32 rows: quad picks row within group-of-4, l16 picks 16B chunk
#pragma unroll
    for (int rr = 0; rr < 8; ++rr) {
        int r = (wv << 5) + (rr << 2) + quad;
        int gr = m0 + r;
        if (gr >= E) continue;
        int cs = (l16 * 8) ^ (((r >> 2) & 3) << 4);
        bf16x8 v = *(const bf16x8*)(sT + r * 128 + cs);
        *(bf16x8*)(ebf + (size_t)perm[gr] * 128 + l16 * 8) = v;
    }
}

// hb0b[n][0:224]=bf16(emb_w[z[n]]), [224:256]=bf16(tag_emb_w[tag[n]])
__global__ __launch_bounds__(256)
void node_gather(const int* __restrict__ z, const int* __restrict__ tag,
                 const float* __restrict__ embw, const float* __restrict__ tembw,
                 unsigned short* __restrict__ hb0b, int N)
{
    int lane = threadIdx.x & 63;
    int n = blockIdx.x * 4 + (threadIdx.x >> 6);
    if (n >= N) return;
    int f = lane * 4;
    float4 v;
    if (f < 224) v = *(const float4*)(embw + (size_t)z[n] * 224 + f);
    else         v = *(const float4*)(tembw + (size_t)tag[n] * 32 + (f - 224));
    ushort4 pk;
    pk.x = (unsigned short)f2bf(v.x);
    pk.y = (unsigned short)f2bf(v.y);
    pk.z = (unsigned short)f2bf(v.z);
    pk.w = (unsigned short)f2bf(v.w);
    *(ushort4*)(hb0b + (size_t)n * 256 + f) = pk;
}

// all bf16 weight conversions in one launch; dst ranges are contiguous in wbuf
__global__ __launch_bounds__(256)
void cvt_all(const float* __restrict__ le2, const float* __restrict__ geom,
             const float* __restrict__ down, const float* __restrict__ up,
             const float* __restrict__ lin, const float* __restrict__ lin2,
             const float* __restrict__ o1, unsigned short* __restrict__ dst)
{
    int i = blockIdx.x * 256 + threadIdx.x;
    if (i >= 425984) return;
    float v;
    if      (i <  16384) v = le2[i];
    else if (i <  65536) v = geom[i - 16384];
    else if (i < 163840) v = down[i - 65536];
    else if (i < 262144) v = up[i - 163840];
    else if (i < 327680) v = lin[i - 262144];
    else if (i < 393216) v = lin2[i - 327680];
    else                 v = o1[i - 393216];
    dst[i] = (unsigned short)f2bf(v);
}

// ---- counting sort by dst ----
__global__ __launch_bounds__(256)
void edge_hist(const int* __restrict__ dst, int* __restrict__ cnt, int E)
{
    for (int i = blockIdx.x * 256 + threadIdx.x; i < E; i += gridDim.x * 256)
        atomicAdd(&cnt[dst[i]], 1);
}

__global__ __launch_bounds__(1024)
void scan_excl(int* __restrict__ cnt, int N)
{
    __shared__ int sdata[1024];
    __shared__ int s_carry;
    int tid = threadIdx.x;
    if (tid == 0) s_carry = 0;
    __syncthreads();
    for (int base = 0; base < N; base += 1024) {
        int i = base + tid;
        int v = (i < N) ? cnt[i] : 0;
        sdata[tid] = v;
        __syncthreads();
        for (int off = 1; off < 1024; off <<= 1) {
            int t = (tid >= off) ? sdata[tid - off] : 0;
            __syncthreads();
            sdata[tid] += t;
            __syncthreads();
        }
        int excl = sdata[tid] - v + s_carry;
        if (i < N) cnt[i] = excl;
        int tot = sdata[1023];
        __syncthreads();
        if (tid == 0) s_carry += tot;
        __syncthreads();
    }
}

__global__ __launch_bounds__(256)
void edge_rank(const int* __restrict__ src, const int* __restrict__ dst,
               int* __restrict__ cursor, int* __restrict__ rank,
               int* __restrict__ src_s, int E)
{
    for (int i = blockIdx.x * 256 + threadIdx.x; i < E; i += gridDim.x * 256) {
        int d = dst[i];
        int p = atomicAdd(&cursor[d], 1);
        rank[i] = p;
        src_s[p] = src[i];
    }
}

// CSR segment-sum: one wave per node d; agg[d] = sum el[p]*hd[src_s[p]]
// Unrolled 4x: 8 outstanding 256B loads per wave (MLP).
__global__ __launch_bounds__(256)
void csr_gather(const unsigned int* __restrict__ el2,
                const unsigned int* __restrict__ hd2,
                const int* __restrict__ src_s,
                const int* __restrict__ rowend,
                float* __restrict__ agg, int N)
{
    int lane = threadIdx.x & 63;
    int d = blockIdx.x * 4 + (threadIdx.x >> 6);
    if (d >= N) return;
    int start = (d == 0) ? 0 : rowend[d - 1];
    int end = rowend[d];
    float a0 = 0.f, a1 = 0.f;
    int p = start;
    for (; p + 3 < end; p += 4) {
        int s0 = src_s[p], s1 = src_s[p + 1], s2 = src_s[p + 2], s3 = src_s[p + 3];
        unsigned int e0 = el2[(size_t)p * 64 + lane];
        unsigned int e1 = el2[(size_t)(p + 1) * 64 + lane];
        unsigned int e2 = el2[(size_t)(p + 2) * 64 + lane];
        unsigned int e3 = el2[(size_t)(p + 3) * 64 + lane];
        unsigned int h0 = hd2[(size_t)s0 * 64 + lane];
        unsigned int h1 = hd2[(size_t)s1 * 64 + lane];
        unsigned int h2 = hd2[(size_t)s2 * 64 + lane];
        unsigned int h3 = hd2[(size_t)s3 * 64 + lane];
        a0 = fmaf(bf2f(e0 & 0xffffu), bf2f(h0 & 0xffffu), a0);
        a1 = fmaf(bf2f(e0 >> 16),     bf2f(h0 >> 16),     a1);
        a0 = fmaf(bf2f(e1 & 0xffffu), bf2f(h1 & 0xffffu), a0);
        a1 = fmaf(bf2f(e1 >> 16),     bf2f(h1 >> 16),     a1);
        a0 = fmaf(bf2f(e2 & 0xffffu), bf2f(h2 & 0xffffu), a0);
        a1 = fmaf(bf2f(e2 >> 16),     bf2f(h2 >> 16),     a1);
        a0 = fmaf(bf2f(e3 & 0xffffu), bf2f(h3 & 0xffffu), a0);
        a1 = fmaf(bf2f(e3 >> 16),     bf2f(h3 >> 16),     a1);
    }
    for (; p < end; ++p) {
        int s0 = src_s[p];
        unsigned int e0 = el2[(size_t)p * 64 + lane];
        unsigned int h0 = hd2[(size_t)s0 * 64 + lane];
        a0 = fmaf(bf2f(e0 & 0xffffu), bf2f(h0 & 0xffffu), a0);
        a1 = fmaf(bf2f(e0 >> 16),     bf2f(h0 >> 16),     a1);
    }
    *(float2*)(agg + (size_t)d * 128 + 2 * lane) = make_float2(a0, a1);
}

__global__ __launch_bounds__(256)
void gn_stats(const float* __restrict__ agg, float* __restrict__ sums, int N)
{
    __shared__ float red[512];
    int f = threadIdx.x & 127;
    int sub = threadIdx.x >> 7;
    float s = 0.f, s2 = 0.f;
    for (int r = blockIdx.x * 2 + sub; r < N; r += gridDim.x * 2) {
        float v = agg[(size_t)r * 128 + f];
        s += v;
        s2 += v * v;
    }
    red[threadIdx.x] = s;
    red[256 + threadIdx.x] = s2;
    __syncthreads();
    if (sub == 0) {
        s = red[f] + red[128 + f];
        s2 = red[256 + f] + red[384 + f];
        atomicAdd(&sums[f], s);
        atomicAdd(&sums[128 + f], s2);
    }
}

__global__ void gn_finalize(const float* __restrict__ sums,
                            const float* __restrict__ gnw, const float* __restrict__ gnb,
                            const float* __restrict__ gnms, float* __restrict__ ab,
                            float invN)
{
    int f = threadIdx.x; // 128
    float mean = sums[f] * invN;
    float ex2 = sums[128 + f] * invN;
    float m2 = mean * gnms[f];
    float var = ex2 - 2.f * m2 * mean + m2 * m2;
    float rstd = 1.0f / sqrtf(var + EPS_GN);
    float a = gnw[f] * rstd;
    ab[f] = a;
    ab[128 + f] = gnb[f] - a * m2;
}

// ga = bf16(silu(a*agg+b)) elementwise
__global__ __launch_bounds__(256)
void gn_apply(const float* __restrict__ agg, const float* __restrict__ ab,
              unsigned int* __restrict__ ga, int n2 /* N*64 */)
{
    for (int i = blockIdx.x * 256 + threadIdx.x; i < n2; i += gridDim.x * 256) {
        int f = (i & 63) * 2;
        float2 v = *(const float2*)(agg + (size_t)i * 2);
        float r0 = silu_f(ab[f] * v.x + ab[128 + f]);
        float r1 = silu_f(ab[f + 1] * v.y + ab[129 + f]);
        ga[i] = f2bf(r0) | (f2bf(r1) << 16);
    }
}

// out[g] += per-graph sum of (h1[r].w2)+b2 over sorted batch, run-accumulated.
__global__ __launch_bounds__(256)
void out_reduce(const float* __restrict__ h1, const float* __restrict__ w2,
                const float* __restrict__ b2, const int* __restrict__ batch,
                float* __restrict__ out, int N)
{
    int lane = threadIdx.x & 63;
    int wid = blockIdx.x * 4 + (threadIdx.x >> 6);
    int nwaves = gridDim.x * 4;
    int chunk = (N + nwaves - 1) / nwaves;
    int r0 = wid * chunk;
    int r1 = r0 + chunk; if (r1 > N) r1 = N;
    if (r0 >= r1) return;
    float wa = w2[lane], wb = w2[64 + lane];
    float bb = b2[0];
    int cur = batch[r0];
    float acc = 0.f;
    int cnt = 0;
    for (int r = r0; r < r1; ++r) {
        int g = batch[r];
        if (g != cur) {
            float v = acc;
#pragma unroll
            for (int o = 32; o > 0; o >>= 1) v += __shfl_down(v, o);
            if (lane == 0) atomicAdd(&out[cur], v + (float)cnt * bb);
            cur = g; acc = 0.f; cnt = 0;
        }
        acc = fmaf(h1[(size_t)r * 128 + lane], wa, acc);
        acc = fmaf(h1[(size_t)r * 128 + 64 + lane], wb, acc);
        ++cnt;
    }
    float v = acc;
#pragma unroll
    for (int o = 32; o > 0; o >>= 1) v += __shfl_down(v, o);
    if (lane == 0) atomicAdd(&out[cur], v + (float)cnt * bb);
}

extern "C" void kernel_launch(void* const* d_in, const int* in_sizes, int n_in,
                              void* d_out, int out_size, void* d_ws, size_t ws_size,
                              hipStream_t stream)
{
    const int*   z         = (const int*)d_in[0];
    const int*   tag       = (const int*)d_in[1];
    const float* rel_pos   = (const float*)d_in[2];
    const float* edge_attr = (const float*)d_in[3];
    const int*   eidx      = (const int*)d_in[4];
    const int*   batch     = (const int*)d_in[5];
    const float* le1w  = (const float*)d_in[6];
    const float* le1b  = (const float*)d_in[7];
    const float* le12w = (const float*)d_in[8];
    const float* le12b = (const float*)d_in[9];
    const float* le2w  = (const float*)d_in[10];
    const float* le2b  = (const float*)d_in[11];
    const float* embw  = (const float*)d_in[12];
    const float* tembw = (const float*)d_in[13];
    const float* linw  = (const float*)d_in[14];
    const float* linb  = (const float*)d_in[15];
    const float* lin2w = (const float*)d_in[16];
    const float* lin2b = (const float*)d_in[17];
    const float* geomw = (const float*)d_in[18];
    const float* geomb = (const float*)d_in[19];
    const float* downw = (const float*)d_in[20];
    const float* downb = (const float*)d_in[21];
    const float* upw   = (const float*)d_in[22];
    const float* upb   = (const float*)d_in[23];
    const float* gnw   = (const float*)d_in[24];
    const float* gnb   = (const float*)d_in[25];
    const float* gnms  = (const float*)d_in[26];
    const float* o1w   = (const float*)d_in[27];
    const float* o1b   = (const float*)d_in[28];
    const float* o2w   = (const float*)d_in[29];
    const float* o2b   = (const float*)d_in[30];

    const int N = in_sizes[0];
    const int E = in_sizes[2] / 3;
    const int* esrc = eidx;
    const int* edst = eidx + E;

    char* ws = (char*)d_ws;
    size_t off = 0;
    unsigned short* T = (unsigned short*)(ws + off); off += (size_t)E * 128 * 2;   // hb0b+t1b / el / eapad
    unsigned short* ebf = (unsigned short*)(ws + off); off += (size_t)E * 128 * 2;
    float* h   = (float*)(ws + off); off += (size_t)N * 256 * 4;
    float* agg = (float*)(ws + off); off += (size_t)N * 128 * 4;
    unsigned short* hdb = (unsigned short*)(ws + off); off += (size_t)N * 128 * 2;
    int*   cnt   = (int*)(ws + off); off += (size_t)N * 4;
    int*   src_s = (int*)(ws + off); off += (size_t)E * 4;
    unsigned short* wbuf = (unsigned short*)(ws + off); off += 442368ull * 2;
    float* stats = (float*)(ws + off); off += 256 * 4;
    float* ab    = (float*)(ws + off); off += 256 * 4;
    float* bcat  = (float*)(ws + off); off += 128;

    // aliases
    unsigned short* eapad = T;                      // E*64 bf16 (dead after edge_embed)
    unsigned short* hb0b = T;                       // N*256 bf16 (after edge_embed)
    unsigned short* t1b  = T + (size_t)N * 256;     // N*256 bf16 (dead before layers)
    unsigned short* el = T;                         // E*128 bf16 (layers)
    int*   rank = (int*)agg;                        // E ints, dead before agg first write
    unsigned short* ga = hdb;                       // bf16 N*128, written after csr_gather
    float* h1 = agg;                                // N*128 f32, written after agg last read

    // bf16 weight buffer offsets
    unsigned short* wb_le2  = wbuf;                 // 16384
    unsigned short* wb_geom = wbuf + 16384;         // 3*16384
    unsigned short* wb_down = wbuf + 65536;         // 3*32768
    unsigned short* wb_up   = wbuf + 163840;        // 3*32768
    unsigned short* wb_lin  = wbuf + 262144;        // 65536
    unsigned short* wb_lin2 = wbuf + 327680;        // 65536
    unsigned short* wb_o1   = wbuf + 393216;        // 32768
    unsigned short* wb_cat  = wbuf + 425984;        // 8192

    const int mbE = (E + 127) / 128;
    const int mbN = (N + 127) / 128;
    dim3 blk(256);

    // weight conversions (one fused launch) + wcat + eapad
    cvt_all<<<dim3(1664), blk, 0, stream>>>(
        le2w, geomw, downw, upw, linw, lin2w, o1w, wbuf);
    build_wcat<<<dim3(32), blk, 0, stream>>>(le1w, le12w, le1b, le12b, wb_cat, bcat);
    build_eapad<<<dim3((E * 8 + 255) / 256), blk, 0, stream>>>(
        rel_pos, edge_attr, eapad, E);

    // counting sort by dst
    hipMemsetAsync(cnt, 0, (size_t)N * sizeof(int), stream);
    edge_hist<<<dim3(3125), blk, 0, stream>>>(edst, cnt, E);
    scan_excl<<<dim3(1), dim3(1024), 0, stream>>>(cnt, N);
    edge_rank<<<dim3(3125), blk, 0, stream>>>(esrc, edst, cnt, rank, src_s, E);

    // fused edge embedding (permuted into dst-sorted order)
    edge_embed_fused<<<dim3(mbE), blk, 0, stream>>>(
        eapad, wb_cat, bcat, wb_le2, le2b, rank, ebf, E);

    // node embedding: hb0b -> t1b -> h  (bf16 activations; hb0b aliases eapad)
    node_gather<<<dim3((N + 3) / 4), blk, 0, stream>>>(z, tag, embw, tembw, hb0b, N);
    mgemm<256, A_BF16, ME_STORE_BF16, false><<<dim3(mbN, 2), blk, 0, stream>>>(
        hb0b, wb_lin, linb, nullptr, t1b, N, 256, nullptr);
    mgemm<256, A_BF16, ME_STORE_F32, false><<<dim3(mbN, 2), blk, 0, stream>>>(
        t1b, wb_lin2, lin2b, h, nullptr, N, 256, nullptr);

    // interaction blocks
    for (int l = 0; l < 3; ++l) {
        mgemm<256, A_F32, ME_STORE_BF16, false><<<dim3(mbN, 1), blk, 0, stream>>>(
            h, wb_down + (size_t)l * 32768, downb + (size_t)l * 128,
            nullptr, hdb, N, 128, nullptr);
        mgemm_bs<ME_STORE_BF16><<<dim3(mbE, 1), blk, 0, stream>>>(
            ebf, wb_geom + (size_t)l * 16384, geomb + (size_t)l * 128,
            nullptr, el, E, 128);
        csr_gather<<<dim3((N + 3) / 4), blk, 0, stream>>>(
            (const unsigned int*)el, (const unsigned int*)hdb, src_s, cnt, agg, N);
        hipMemsetAsync(stats, 0, 256 * sizeof(float), stream);
        gn_stats<<<dim3(256), blk, 0, stream>>>(agg, stats, N);
        gn_finalize<<<dim3(1), dim3(128), 0, stream>>>(
            stats, gnw + (size_t)l * 128, gnb + (size_t)l * 128,
            gnms + (size_t)l * 128, ab, 1.0f / (float)N);
        gn_apply<<<dim3(512), blk, 0, stream>>>(agg, ab, (unsigned int*)ga, N * 64);
        mgemm_bs<ME_RESID><<<dim3(mbN, 2), blk, 0, stream>>>(
            ga, wb_up + (size_t)l * 32768, upb + (size_t)l * 256,
            h, nullptr, N, 256);
    }

    // readout
    mgemm<256, A_F32, ME_STORE_F32, false><<<dim3(mbN, 1), blk, 0, stream>>>(
        h, wb_o1, o1b, h1, nullptr, N, 128, nullptr);
    hipMemsetAsync(d_out, 0, 32 * sizeof(float), stream);
    out_reduce<<<dim3(512), blk, 0, stream>>>(h1, o2w, o2b, batch, (float*)d_out, N);
}

// Round 10
// 1555.085 us; speedup vs baseline: 1.4088x; 1.0102x over previous
//
#include <hip/hip_runtime.h>
#include <math.h>

// FAENet forward. All GEMMs via bf16 MFMA (16x16x32), fp32 accumulate.
// KEY LAYOUT TRICK (r3): mfma operands SWAPPED -> mfma(W_frag, A_frag, acc).
// Lane holds 1 output row x 4 CONSECUTIVE cols -> vectorized epilogues.
// r9: all f32->bf16 pair conversions via v_cvt_pk_bf16_f32 (1 instr vs ~8
// for hand-rolled integer RNE; gfx950-native, RNE rounding). Applied to all
// bf16 epilogues, the A_F32 fragment repack, node_gather/eapad/gn_apply.
// csr_gather unrolled 8x (16 outstanding 256B streams/wave).
// r8: bf16 activations end-to-end; generalized bf16 mgemm epilogue.
// r7: mgemm_bs for A_BF16 K=128 GEMMs (geom, up): LDS-staged A tile.
// r4: build_eapad pre-pass -> edge stage-1 A loads direct from global.
// out_reduce: contiguous per-wave chunks over sorted batch (~2K atomics).
// silu: v_rcp_f32 instead of IEEE divide (~1ulp; bf16 output absorbs it).

#define EPS_GN 1e-5f

typedef __attribute__((ext_vector_type(8))) short bf16x8;
typedef __attribute__((ext_vector_type(4))) float f32x4;

__device__ __forceinline__ float silu_f(float x) {
    float e = __expf(-x);
    return x * __builtin_amdgcn_rcpf(1.0f + e);
}
__device__ __forceinline__ float bf2f(unsigned int u) {
    union { unsigned int i; float f; } c;
    c.i = u << 16;
    return c.f;
}
__device__ __forceinline__ unsigned int f2bf(float x) {
    union { float f; unsigned int i; } c;
    c.f = x;
    unsigned int r = c.i + 0x7fffu + ((c.i >> 16) & 1u);
    return r >> 16;
}
// packed pair: low16 = bf16(a), high16 = bf16(b); RNE (gfx950 v_cvt_pk).
__device__ __forceinline__ unsigned int cvtpk(float a, float b) {
    unsigned int r;
    asm("v_cvt_pk_bf16_f32 %0, %1, %2" : "=v"(r) : "v"(a), "v"(b));
    return r;
}

enum { A_BF16 = 0, A_F32 = 1 };
enum { ME_STORE_F32 = 0, ME_STORE_BF16 = 1, ME_PERM_BF16 = 2, ME_RESID = 3 };

// C[M x NFTOT] = epi(A[M x K] @ W[NFTOT x K]^T + bias), MFMA bf16.
// acc[tm][tn] layout (operand-swapped): lane row = 16*tm + l16,
// cols = 16*tn + quad*4 + rg (4 consecutive features per lane).
// bf16 epilogue: NFTOT multiple of 128; each (bx,by) block stores 128 rows
// x 128-col half at col base by*128 (full 256B contiguous segments).
// ME_PERM_BF16 additionally requires NFTOT==128 (perm indexes full rows).
template<int K, int AMODE, int EPI, bool PRELW>
__global__ __launch_bounds__(256)
void mgemm(const void* __restrict__ Ap, const unsigned short* __restrict__ Wp,
           const float* __restrict__ bias, float* __restrict__ Cf,
           unsigned short* __restrict__ Cb, int M, int NFTOT,
           const int* __restrict__ perm)
{
    constexpr int KS = K / 32;
    const int tid = threadIdx.x;
    const int lane = tid & 63;
    const int wv = tid >> 6;                    // 0..3
    const int l16 = lane & 15;
    const int quad = lane >> 4;                 // 0..3
    const int m0 = blockIdx.x * 128 + (wv >> 1) * 64;
    const int n0 = blockIdx.y * 128 + (wv & 1) * 64;

    bf16x8 wpre[PRELW ? (KS * 4) : 1];
    if (PRELW) {
#pragma unroll
        for (int t = 0; t < 4; ++t)
#pragma unroll
            for (int s = 0; s < KS; ++s)
                wpre[t * KS + s] = *(const bf16x8*)(Wp +
                    (size_t)(n0 + 16 * t + l16) * K + s * 32 + quad * 8);
    }

    f32x4 acc[4][4];
#pragma unroll
    for (int i = 0; i < 4; ++i)
#pragma unroll
        for (int j = 0; j < 4; ++j) acc[i][j] = (f32x4){0.f, 0.f, 0.f, 0.f};

    for (int s = 0; s < KS; ++s) {
        bf16x8 af[4];
#pragma unroll
        for (int t = 0; t < 4; ++t) {
            int r = m0 + 16 * t + l16;
            if (r >= M) r = M - 1;
            if (AMODE == A_BF16) {
                af[t] = *(const bf16x8*)((const unsigned short*)Ap +
                                         (size_t)r * K + s * 32 + quad * 8);
            } else {
                const float* ap = (const float*)Ap + (size_t)r * K + s * 32 + quad * 8;
                float4 x0 = *(const float4*)ap;
                float4 x1 = *(const float4*)(ap + 4);
                uint4 u;
                u.x = cvtpk(x0.x, x0.y);
                u.y = cvtpk(x0.z, x0.w);
                u.z = cvtpk(x1.x, x1.y);
                u.w = cvtpk(x1.z, x1.w);
                af[t] = *(bf16x8*)&u;
            }
        }
        bf16x8 wf[4];
#pragma unroll
        for (int t = 0; t < 4; ++t) {
            if (PRELW) wf[t] = wpre[t * KS + s];
            else       wf[t] = *(const bf16x8*)(Wp +
                           (size_t)(n0 + 16 * t + l16) * K + s * 32 + quad * 8);
        }
#pragma unroll
        for (int tm = 0; tm < 4; ++tm)
#pragma unroll
            for (int tn = 0; tn < 4; ++tn)
                acc[tm][tn] = __builtin_amdgcn_mfma_f32_16x16x32_bf16(
                    wf[tn], af[tm], acc[tm][tn], 0, 0, 0);
    }

    if constexpr (EPI == ME_STORE_BF16 || EPI == ME_PERM_BF16) {
        // silu -> LDS (quad-XOR swizzle, b64 writes) -> cooperative row
        // store: each wave stores 32 x 256B row-halves, 16B/lane, full lines.
        __shared__ unsigned short sOut[128 * 128];
        const int mwl = (wv >> 1) * 64;
        const int nwl = (wv & 1) * 64;
        const int cbase = blockIdx.y * 128;
        const int key = (l16 >> 2) & 3;   // == (local_row>>2)&3
#pragma unroll
        for (int tn = 0; tn < 4; ++tn) {
            int cb = nwl + 16 * tn + quad * 4;
            float4 bv = *(const float4*)(bias + cbase + cb);
            int cs = cb ^ (key << 4);
#pragma unroll
            for (int tm = 0; tm < 4; ++tm) {
                int r = mwl + 16 * tm + l16;
                uint2 pk;
                pk.x = cvtpk(silu_f(acc[tm][tn][0] + bv.x),
                             silu_f(acc[tm][tn][1] + bv.y));
                pk.y = cvtpk(silu_f(acc[tm][tn][2] + bv.z),
                             silu_f(acc[tm][tn][3] + bv.w));
                *(uint2*)(sOut + r * 128 + cs) = pk;
            }
        }
        __syncthreads();
#pragma unroll
        for (int rr = 0; rr < 8; ++rr) {
            int r = (wv << 5) + (rr << 2) + quad;
            int gr = blockIdx.x * 128 + r;
            if (gr >= M) continue;
            int cs = (l16 * 8) ^ (((r >> 2) & 3) << 4);
            bf16x8 v = *(const bf16x8*)(sOut + r * 128 + cs);
            int dr = (EPI == ME_PERM_BF16) ? perm[gr] : gr;
            *(bf16x8*)(Cb + (size_t)dr * NFTOT + cbase + l16 * 8) = v;
        }
    } else {
        // f32 path: 4 consecutive cols per lane -> float4 stores (full lines).
#pragma unroll
        for (int tn = 0; tn < 4; ++tn) {
            int cb = n0 + 16 * tn + quad * 4;
            float4 bv = *(const float4*)(bias + cb);
#pragma unroll
            for (int tm = 0; tm < 4; ++tm) {
                int r = m0 + 16 * tm + l16;
                if (r >= M) continue;
                float4 v;
                v.x = silu_f(acc[tm][tn][0] + bv.x);
                v.y = silu_f(acc[tm][tn][1] + bv.y);
                v.z = silu_f(acc[tm][tn][2] + bv.z);
                v.w = silu_f(acc[tm][tn][3] + bv.w);
                float* dst = Cf + (size_t)r * NFTOT + cb;
                if (EPI == ME_STORE_F32) {
                    *(float4*)dst = v;
                } else { // ME_RESID
                    float4 o = *(const float4*)dst;
                    o.x += v.x; o.y += v.y; o.z += v.z; o.w += v.w;
                    *(float4*)dst = o;
                }
            }
        }
    }
}

// A_BF16, K=128 GEMM with LDS-staged A tile (geom / up). The 128x128 bf16 A
// tile is staged via 8 coalesced 16B loads/thread -> XOR-swizzled ds_write
// (chunk ^= r&7 kills the stride-256B bank conflict). Puts 32KB/block in
// flight during staging. W streams from L2 (no preload).
// EPI==ME_STORE_BF16 requires NFTOT==128, gridDim.y==1 (sOut aliases aT).
template<int EPI>
__global__ __launch_bounds__(256)
void mgemm_bs(const unsigned short* __restrict__ Ap,
              const unsigned short* __restrict__ Wp,
              const float* __restrict__ bias, float* __restrict__ Cf,
              unsigned short* __restrict__ Cb, int M, int NFTOT)
{
    __shared__ unsigned short aT[128 * 128];   // 32KB; reused as sOut in bf16 epi
    const int tid = threadIdx.x;
    const int lane = tid & 63;
    const int wv = tid >> 6;
    const int l16 = lane & 15;
    const int quad = lane >> 4;
    const int m0b = blockIdx.x * 128;
    const int mw = (wv >> 1) * 64;
    const int nw = (wv & 1) * 64;
    const int n0 = blockIdx.y * 128 + nw;

    // stage A tile: 16 rows per 256-thread step, 16B/thread, rows clamped
    bf16x8 st[8];
#pragma unroll
    for (int i = 0; i < 8; ++i) {
        int L = i * 256 + tid;
        int r = L >> 4, c = L & 15;
        int rg = m0b + r; if (rg >= M) rg = M - 1;
        st[i] = *(const bf16x8*)(Ap + (size_t)rg * 128 + c * 8);
    }
#pragma unroll
    for (int i = 0; i < 8; ++i) {
        int L = i * 256 + tid;
        int r = L >> 4, c = L & 15;
        *(bf16x8*)(aT + r * 128 + (c ^ (r & 7)) * 8) = st[i];
    }
    __syncthreads();

    f32x4 acc[4][4];
#pragma unroll
    for (int i = 0; i < 4; ++i)
#pragma unroll
        for (int j = 0; j < 4; ++j) acc[i][j] = (f32x4){0.f, 0.f, 0.f, 0.f};

#pragma unroll
    for (int s = 0; s < 4; ++s) {
        bf16x8 af[4], wf[4];
#pragma unroll
        for (int t = 0; t < 4; ++t) {
            int r = mw + 16 * t + l16;
            int ch = (4 * s + quad) ^ (r & 7);
            af[t] = *(const bf16x8*)(aT + r * 128 + ch * 8);
        }
#pragma unroll
        for (int t = 0; t < 4; ++t)
            wf[t] = *(const bf16x8*)(Wp +
                (size_t)(n0 + 16 * t + l16) * 128 + s * 32 + quad * 8);
#pragma unroll
        for (int tm = 0; tm < 4; ++tm)
#pragma unroll
            for (int tn = 0; tn < 4; ++tn)
                acc[tm][tn] = __builtin_amdgcn_mfma_f32_16x16x32_bf16(
                    wf[tn], af[tm], acc[tm][tn], 0, 0, 0);
    }

    if constexpr (EPI == ME_STORE_BF16) {
        __syncthreads();   // all waves done reading aT before reuse as sOut
        unsigned short* sOut = aT;
        const int key = (l16 >> 2) & 3;
#pragma unroll
        for (int tn = 0; tn < 4; ++tn) {
            int cb = nw + 16 * tn + quad * 4;
            float4 bv = *(const float4*)(bias + cb);
            int cs = cb ^ (key << 4);
#pragma unroll
            for (int tm = 0; tm < 4; ++tm) {
                int r = mw + 16 * tm + l16;
                uint2 pk;
                pk.x = cvtpk(silu_f(acc[tm][tn][0] + bv.x),
                             silu_f(acc[tm][tn][1] + bv.y));
                pk.y = cvtpk(silu_f(acc[tm][tn][2] + bv.z),
                             silu_f(acc[tm][tn][3] + bv.w));
                *(uint2*)(sOut + r * 128 + cs) = pk;
            }
        }
        __syncthreads();
#pragma unroll
        for (int rr = 0; rr < 8; ++rr) {
            int r = (wv << 5) + (rr << 2) + quad;
            int gr = m0b + r;
            if (gr >= M) continue;
            int cs = (l16 * 8) ^ (((r >> 2) & 3) << 4);
            bf16x8 v = *(const bf16x8*)(sOut + r * 128 + cs);
            *(bf16x8*)(Cb + (size_t)gr * 128 + l16 * 8) = v;
        }
    } else { // ME_RESID (f32, NFTOT wide)
#pragma unroll
        for (int tn = 0; tn < 4; ++tn) {
            int cb = n0 + 16 * tn + quad * 4;
            float4 bv = *(const float4*)(bias + cb);
#pragma unroll
            for (int tm = 0; tm < 4; ++tm) {
                int r = m0b + mw + 16 * tm + l16;
                if (r >= M) continue;
                float* dst = Cf + (size_t)r * NFTOT + cb;
                float4 o = *(const float4*)dst;
                o.x += silu_f(acc[tm][tn][0] + bv.x);
                o.y += silu_f(acc[tm][tn][1] + bv.y);
                o.z += silu_f(acc[tm][tn][2] + bv.z);
                o.w += silu_f(acc[tm][tn][3] + bv.w);
                *(float4*)dst = o;
            }
        }
    }
}

// Wcat[128 x 64] bf16 matching eapad layout [rp k=0..2 | ea k=3..52 | pad]:
// rows 0..63: le1w at cols 0..2; rows 64..127: le12w at cols 3..52; rest 0.
// bcat[128] = [le1b | le12b].
__global__ __launch_bounds__(256)
void build_wcat(const float* __restrict__ w1, const float* __restrict__ w12,
                const float* __restrict__ b1, const float* __restrict__ b12,
                unsigned short* __restrict__ wcat, float* __restrict__ bcat)
{
    int i = blockIdx.x * 256 + threadIdx.x;
    if (i < 8192) {
        int r = i >> 6, c = i & 63;
        float v = 0.f;
        if (r < 64) { if (c < 3) v = w1[r * 3 + c]; }
        else        { if (c >= 3 && c < 53) v = w12[(r - 64) * 50 + (c - 3)]; }
        wcat[i] = (unsigned short)f2bf(v);
    }
    if (i < 128) bcat[i] = (i < 64) ? b1[i] : b12[i - 64];
}

// eapad[e][0:64] = bf16([rp[e][0..2] | ea[e][0..49] | zeros]), one 16B store
// per thread (fully coalesced). Feeds stage-1 A loads directly from global.
__global__ __launch_bounds__(256)
void build_eapad(const float* __restrict__ rp, const float* __restrict__ ea,
                 unsigned short* __restrict__ out, int E)
{
    int g = blockIdx.x * 256 + threadIdx.x;     // 16B group index
    if (g >= E * 8) return;
    int e = g >> 3, sub = g & 7;
    float xs[8];
#pragma unroll
    for (int j = 0; j < 8; ++j) {
        int c = sub * 8 + j;
        float x = 0.f;
        if (c < 3)       x = rp[(size_t)e * 3 + c];
        else if (c < 53) x = ea[(size_t)e * 50 + (c - 3)];
        xs[j] = x;
    }
    uint4 v;
    v.x = cvtpk(xs[0], xs[1]);
    v.y = cvtpk(xs[2], xs[3]);
    v.z = cvtpk(xs[4], xs[5]);
    v.w = cvtpk(xs[6], xs[7]);
    *(uint4*)(out + (size_t)g * 8) = v;
}

// Fused edge embedding: e[perm[r]] = silu(silu(eapad @ Wcat^T + bcat) @ W2^T + b2)
// Operand-swapped MFMA; stage-1 A direct from global; LDS = sT only (32KB).
__global__ __launch_bounds__(256)
void edge_embed_fused(const unsigned short* __restrict__ eapad,
                      const unsigned short* __restrict__ wcat,
                      const float* __restrict__ bcat,
                      const unsigned short* __restrict__ w2,
                      const float* __restrict__ b2,
                      const int* __restrict__ perm,
                      unsigned short* __restrict__ ebf, int E)
{
    __shared__ unsigned short sT[128 * 128];   // 32 KB t-tile
    const int tid = threadIdx.x;
    const int m0 = blockIdx.x * 128;

    const int lane = tid & 63;
    const int wv = tid >> 6;
    const int l16 = lane & 15, quad = lane >> 4;
    const int mw = (wv >> 1) * 64;
    const int nw = (wv & 1) * 64;

    // stage 1: t = silu(A @ Wcat^T + bcat), K=64; A fragments from global
    f32x4 acc[4][4];
#pragma unroll
    for (int i = 0; i < 4; ++i)
#pragma unroll
        for (int j = 0; j < 4; ++j) acc[i][j] = (f32x4){0.f, 0.f, 0.f, 0.f};
#pragma unroll
    for (int s = 0; s < 2; ++s) {
        bf16x8 af[4], wf[4];
#pragma unroll
        for (int t = 0; t < 4; ++t) {
            int r = m0 + mw + 16 * t + l16;
            if (r >= E) r = E - 1;
            af[t] = *(const bf16x8*)(eapad + (size_t)r * 64 + s * 32 + quad * 8);
        }
#pragma unroll
        for (int t = 0; t < 4; ++t)
            wf[t] = *(const bf16x8*)(wcat +
                (size_t)(nw + 16 * t + l16) * 64 + s * 32 + quad * 8);
#pragma unroll
        for (int tm = 0; tm < 4; ++tm)
#pragma unroll
            for (int tn = 0; tn < 4; ++tn)
                acc[tm][tn] = __builtin_amdgcn_mfma_f32_16x16x32_bf16(
                    wf[tn], af[tm], acc[tm][tn], 0, 0, 0);
    }

    // silu+bias -> sT with k-group rotation swizzle, b64 writes:
    // element (r,c) at sT[r*128 + (((c>>3)+r)&15)*8 + (c&7)]
#pragma unroll
    for (int tn = 0; tn < 4; ++tn) {
        int cb = nw + 16 * tn + quad * 4;
        float4 bv = *(const float4*)(bcat + cb);
#pragma unroll
        for (int tm = 0; tm < 4; ++tm) {
            int r = mw + 16 * tm + l16;
            int g = ((cb >> 3) + r) & 15;
            uint2 pk;
            pk.x = cvtpk(silu_f(acc[tm][tn][0] + bv.x),
                         silu_f(acc[tm][tn][1] + bv.y));
            pk.y = cvtpk(silu_f(acc[tm][tn][2] + bv.z),
                         silu_f(acc[tm][tn][3] + bv.w));
            *(uint2*)(sT + r * 128 + g * 8 + (cb & 7)) = pk;
        }
    }
    __syncthreads();

    // stage 2: e = silu(t @ W2^T + b2), K=128 (operand-swapped)
    f32x4 acc2[4][4];
#pragma unroll
    for (int i = 0; i < 4; ++i)
#pragma unroll
        for (int j = 0; j < 4; ++j) acc2[i][j] = (f32x4){0.f, 0.f, 0.f, 0.f};
#pragma unroll
    for (int s = 0; s < 4; ++s) {
        bf16x8 af[4], wf[4];
#pragma unroll
        for (int t = 0; t < 4; ++t) {
            int r = mw + 16 * t + l16;
            int g = (s * 4 + quad + r) & 15;
            af[t] = *(const bf16x8*)(sT + r * 128 + g * 8);
        }
#pragma unroll
        for (int t = 0; t < 4; ++t)
            wf[t] = *(const bf16x8*)(w2 +
                (size_t)(nw + 16 * t + l16) * 128 + s * 32 + quad * 8);
#pragma unroll
        for (int tm = 0; tm < 4; ++tm)
#pragma unroll
            for (int tn = 0; tn < 4; ++tn)
                acc2[tm][tn] = __builtin_amdgcn_mfma_f32_16x16x32_bf16(
                    wf[tn], af[tm], acc2[tm][tn], 0, 0, 0);
    }

    // epilogue: silu -> sT (quad-keyed XOR swizzle, b64 writes) ->
    // cooperative permuted row store (16B/lane, full 64B lines).
    __syncthreads();   // all waves done reading sT before overwrite
#pragma unroll
    for (int tn = 0; tn < 4; ++tn) {
        int cb = nw + 16 * tn + quad * 4;
        float4 bv = *(const float4*)(b2 + cb);
#pragma unroll
        for (int tm = 0; tm < 4; ++tm) {
            int r = mw + 16 * tm + l16;
            int cs = cb ^ (((r >> 2) & 3) << 4);
            uint2 pk;
            pk.x = cvtpk(silu_f(acc2[tm][tn][0] + bv.x),
                         silu_f(acc2[tm][tn][1] + bv.y));
            pk.y = cvtpk(silu_f(acc2[tm][tn][2] + bv.z),
                         silu_f(acc2[tm][tn][3] + bv.w));
            *(uint2*)(sT + r * 128 + cs) = pk;
        }
    }
    __syncthreads();
    // each wave stores 32 rows: quad picks row within group-of-4, l16 picks 16B chunk
#pragma unroll
    for (int rr = 0; rr < 8; ++rr) {
        int r = (wv << 5) + (rr << 2) + quad;
        int gr = m0 + r;
        if (gr >= E) continue;
        int cs = (l16 * 8) ^ (((r >> 2) & 3) << 4);
        bf16x8 v = *(const bf16x8*)(sT + r * 128 + cs);
        *(bf16x8*)(ebf + (size_t)perm[gr] * 128 + l16 * 8) = v;
    }
}

// hb0b[n][0:224]=bf16(emb_w[z[n]]), [224:256]=bf16(tag_emb_w[tag[n]])
__global__ __launch_bounds__(256)
void node_gather(const int* __restrict__ z, const int* __restrict__ tag,
                 const float* __restrict__ embw, const float* __restrict__ tembw,
                 unsigned short* __restrict__ hb0b, int N)
{
    int lane = threadIdx.x & 63;
    int n = blockIdx.x * 4 + (threadIdx.x >> 6);
    if (n >= N) return;
    int f = lane * 4;
    float4 v;
    if (f < 224) v = *(const float4*)(embw + (size_t)z[n] * 224 + f);
    else         v = *(const float4*)(tembw + (size_t)tag[n] * 32 + (f - 224));
    uint2 pk;
    pk.x = cvtpk(v.x, v.y);
    pk.y = cvtpk(v.z, v.w);
    *(uint2*)(hb0b + (size_t)n * 256 + f) = pk;
}

// all bf16 weight conversions in one launch; dst ranges are contiguous in wbuf
__global__ __launch_bounds__(256)
void cvt_all(const float* __restrict__ le2, const float* __restrict__ geom,
             const float* __restrict__ down, const float* __restrict__ up,
             const float* __restrict__ lin, const float* __restrict__ lin2,
             const float* __restrict__ o1, unsigned short* __restrict__ dst)
{
    int i = blockIdx.x * 256 + threadIdx.x;
    if (i >= 425984) return;
    float v;
    if      (i <  16384) v = le2[i];
    else if (i <  65536) v = geom[i - 16384];
    else if (i < 163840) v = down[i - 65536];
    else if (i < 262144) v = up[i - 163840];
    else if (i < 327680) v = lin[i - 262144];
    else if (i < 393216) v = lin2[i - 327680];
    else                 v = o1[i - 393216];
    dst[i] = (unsigned short)f2bf(v);
}

// ---- counting sort by dst ----
__global__ __launch_bounds__(256)
void edge_hist(const int* __restrict__ dst, int* __restrict__ cnt, int E)
{
    for (int i = blockIdx.x * 256 + threadIdx.x; i < E; i += gridDim.x * 256)
        atomicAdd(&cnt[dst[i]], 1);
}

__global__ __launch_bounds__(1024)
void scan_excl(int* __restrict__ cnt, int N)
{
    __shared__ int sdata[1024];
    __shared__ int s_carry;
    int tid = threadIdx.x;
    if (tid == 0) s_carry = 0;
    __syncthreads();
    for (int base = 0; base < N; base += 1024) {
        int i = base + tid;
        int v = (i < N) ? cnt[i] : 0;
        sdata[tid] = v;
        __syncthreads();
        for (int off = 1; off < 1024; off <<= 1) {
            int t = (tid >= off) ? sdata[tid - off] : 0;
            __syncthreads();
            sdata[tid] += t;
            __syncthreads();
        }
        int excl = sdata[tid] - v + s_carry;
        if (i < N) cnt[i] = excl;
        int tot = sdata[1023];
        __syncthreads();
        if (tid == 0) s_carry += tot;
        __syncthreads();
    }
}

__global__ __launch_bounds__(256)
void edge_rank(const int* __restrict__ src, const int* __restrict__ dst,
               int* __restrict__ cursor, int* __restrict__ rank,
               int* __restrict__ src_s, int E)
{
    for (int i = blockIdx.x * 256 + threadIdx.x; i < E; i += gridDim.x * 256) {
        int d = dst[i];
        int p = atomicAdd(&cursor[d], 1);
        rank[i] = p;
        src_s[p] = src[i];
    }
}

// CSR segment-sum: one wave per node d; agg[d] = sum el[p]*hd[src_s[p]]
// Unrolled 8x: 16 outstanding 256B streams per wave (MLP).
__global__ __launch_bounds__(256)
void csr_gather(const unsigned int* __restrict__ el2,
                const unsigned int* __restrict__ hd2,
                const int* __restrict__ src_s,
                const int* __restrict__ rowend,
                float* __restrict__ agg, int N)
{
    int lane = threadIdx.x & 63;
    int d = blockIdx.x * 4 + (threadIdx.x >> 6);
    if (d >= N) return;
    int start = (d == 0) ? 0 : rowend[d - 1];
    int end = rowend[d];
    float a0 = 0.f, a1 = 0.f;
    int p = start;
    for (; p + 7 < end; p += 8) {
        int sv[8];
        unsigned int ev[8], hv[8];
#pragma unroll
        for (int j = 0; j < 8; ++j) sv[j] = src_s[p + j];
#pragma unroll
        for (int j = 0; j < 8; ++j) ev[j] = el2[(size_t)(p + j) * 64 + lane];
#pragma unroll
        for (int j = 0; j < 8; ++j) hv[j] = hd2[(size_t)sv[j] * 64 + lane];
#pragma unroll
        for (int j = 0; j < 8; ++j) {
            a0 = fmaf(bf2f(ev[j] & 0xffffu), bf2f(hv[j] & 0xffffu), a0);
            a1 = fmaf(bf2f(ev[j] >> 16),     bf2f(hv[j] >> 16),     a1);
        }
    }
    for (; p + 1 < end; p += 2) {
        int s0 = src_s[p], s1 = src_s[p + 1];
        unsigned int e0 = el2[(size_t)p * 64 + lane];
        unsigned int e1 = el2[(size_t)(p + 1) * 64 + lane];
        unsigned int h0 = hd2[(size_t)s0 * 64 + lane];
        unsigned int h1 = hd2[(size_t)s1 * 64 + lane];
        a0 = fmaf(bf2f(e0 & 0xffffu), bf2f(h0 & 0xffffu), a0);
        a1 = fmaf(bf2f(e0 >> 16),     bf2f(h0 >> 16),     a1);
        a0 = fmaf(bf2f(e1 & 0xffffu), bf2f(h1 & 0xffffu), a0);
        a1 = fmaf(bf2f(e1 >> 16),     bf2f(h1 >> 16),     a1);
    }
    if (p < end) {
        int s0 = src_s[p];
        unsigned int e0 = el2[(size_t)p * 64 + lane];
        unsigned int h0 = hd2[(size_t)s0 * 64 + lane];
        a0 = fmaf(bf2f(e0 & 0xffffu), bf2f(h0 & 0xffffu), a0);
        a1 = fmaf(bf2f(e0 >> 16),     bf2f(h0 >> 16),     a1);
    }
    *(float2*)(agg + (size_t)d * 128 + 2 * lane) = make_float2(a0, a1);
}

__global__ __launch_bounds__(256)
void gn_stats(const float* __restrict__ agg, float* __restrict__ sums, int N)
{
    __shared__ float red[512];
    int f = threadIdx.x & 127;
    int sub = threadIdx.x >> 7;
    float s = 0.f, s2 = 0.f;
    for (int r = blockIdx.x * 2 + sub; r < N; r += gridDim.x * 2) {
        float v = agg[(size_t)r * 128 + f];
        s += v;
        s2 += v * v;
    }
    red[threadIdx.x] = s;
    red[256 + threadIdx.x] = s2;
    __syncthreads();
    if (sub == 0) {
        s = red[f] + red[128 + f];
        s2 = red[256 + f] + red[384 + f];
        atomicAdd(&sums[f], s);
        atomicAdd(&sums[128 + f], s2);
    }
}

__global__ void gn_finalize(const float* __restrict__ sums,
                            const float* __restrict__ gnw, const float* __restrict__ gnb,
                            const float* __restrict__ gnms, float* __restrict__ ab,
                            float invN)
{
    int f = threadIdx.x; // 128
    float mean = sums[f] * invN;
    float ex2 = sums[128 + f] * invN;
    float m2 = mean * gnms[f];
    float var = ex2 - 2.f * m2 * mean + m2 * m2;
    float rstd = 1.0f / sqrtf(var + EPS_GN);
    float a = gnw[f] * rstd;
    ab[f] = a;
    ab[128 + f] = gnb[f] - a * m2;
}

// ga = bf16(silu(a*agg+b)) elementwise
__global__ __launch_bounds__(256)
void gn_apply(const float* __restrict__ agg, const float* __restrict__ ab,
              unsigned int* __restrict__ ga, int n2 /* N*64 */)
{
    for (int i = blockIdx.x * 256 + threadIdx.x; i < n2; i += gridDim.x * 256) {
        int f = (i & 63) * 2;
        float2 v = *(const float2*)(agg + (size_t)i * 2);
        float r0 = silu_f(ab[f] * v.x + ab[128 + f]);
        float r1 = silu_f(ab[f + 1] * v.y + ab[129 + f]);
        ga[i] = cvtpk(r0, r1);
    }
}

// out[g] += per-graph sum of (h1[r].w2)+b2 over sorted batch, run-accumulated.
__global__ __launch_bounds__(256)
void out_reduce(const float* __restrict__ h1, const float* __restrict__ w2,
                const float* __restrict__ b2, const int* __restrict__ batch,
                float* __restrict__ out, int N)
{
    int lane = threadIdx.x & 63;
    int wid = blockIdx.x * 4 + (threadIdx.x >> 6);
    int nwaves = gridDim.x * 4;
    int chunk = (N + nwaves - 1) / nwaves;
    int r0 = wid * chunk;
    int r1 = r0 + chunk; if (r1 > N) r1 = N;
    if (r0 >= r1) return;
    float wa = w2[lane], wb = w2[64 + lane];
    float bb = b2[0];
    int cur = batch[r0];
    float acc = 0.f;
    int cnt = 0;
    for (int r = r0; r < r1; ++r) {
        int g = batch[r];
        if (g != cur) {
            float v = acc;
#pragma unroll
            for (int o = 32; o > 0; o >>= 1) v += __shfl_down(v, o);
            if (lane == 0) atomicAdd(&out[cur], v + (float)cnt * bb);
            cur = g; acc = 0.f; cnt = 0;
        }
        acc = fmaf(h1[(size_t)r * 128 + lane], wa, acc);
        acc = fmaf(h1[(size_t)r * 128 + 64 + lane], wb, acc);
        ++cnt;
    }
    float v = acc;
#pragma unroll
    for (int o = 32; o > 0; o >>= 1) v += __shfl_down(v, o);
    if (lane == 0) atomicAdd(&out[cur], v + (float)cnt * bb);
}

extern "C" void kernel_launch(void* const* d_in, const int* in_sizes, int n_in,
                              void* d_out, int out_size, void* d_ws, size_t ws_size,
                              hipStream_t stream)
{
    const int*   z         = (const int*)d_in[0];
    const int*   tag       = (const int*)d_in[1];
    const float* rel_pos   = (const float*)d_in[2];
    const float* edge_attr = (const float*)d_in[3];
    const int*   eidx      = (const int*)d_in[4];
    const int*   batch     = (const int*)d_in[5];
    const float* le1w  = (const float*)d_in[6];
    const float* le1b  = (const float*)d_in[7];
    const float* le12w = (const float*)d_in[8];
    const float* le12b = (const float*)d_in[9];
    const float* le2w  = (const float*)d_in[10];
    const float* le2b  = (const float*)d_in[11];
    const float* embw  = (const float*)d_in[12];
    const float* tembw = (const float*)d_in[13];
    const float* linw  = (const float*)d_in[14];
    const float* linb  = (const float*)d_in[15];
    const float* lin2w = (const float*)d_in[16];
    const float* lin2b = (const float*)d_in[17];
    const float* geomw = (const float*)d_in[18];
    const float* geomb = (const float*)d_in[19];
    const float* downw = (const float*)d_in[20];
    const float* downb = (const float*)d_in[21];
    const float* upw   = (const float*)d_in[22];
    const float* upb   = (const float*)d_in[23];
    const float* gnw   = (const float*)d_in[24];
    const float* gnb   = (const float*)d_in[25];
    const float* gnms  = (const float*)d_in[26];
    const float* o1w   = (const float*)d_in[27];
    const float* o1b   = (const float*)d_in[28];
    const float* o2w   = (const float*)d_in[29];
    const float* o2b   = (const float*)d_in[30];

    const int N = in_sizes[0];
    const int E = in_sizes[2] / 3;
    const int* esrc = eidx;
    const int* edst = eidx + E;

    char* ws = (char*)d_ws;
    size_t off = 0;
    unsigned short* T = (unsigned short*)(ws + off); off += (size_t)E * 128 * 2;   // hb0b+t1b / el / eapad
    unsigned short* ebf = (unsigned short*)(ws + off); off += (size_t)E * 128 * 2;
    float* h   = (float*)(ws + off); off += (size_t)N * 256 * 4;
    float* agg = (float*)(ws + off); off += (size_t)N * 128 * 4;
    unsigned short* hdb = (unsigned short*)(ws + off); off += (size_t)N * 128 * 2;
    int*   cnt   = (int*)(ws + off); off += (size_t)N * 4;
    int*   src_s = (int*)(ws + off); off += (size_t)E * 4;
    unsigned short* wbuf = (unsigned short*)(ws + off); off += 442368ull * 2;
    float* stats = (float*)(ws + off); off += 256 * 4;
    float* ab    = (float*)(ws + off); off += 256 * 4;
    float* bcat  = (float*)(ws + off); off += 128;

    // aliases
    unsigned short* eapad = T;                      // E*64 bf16 (dead after edge_embed)
    unsigned short* hb0b = T;                       // N*256 bf16 (after edge_embed)
    unsigned short* t1b  = T + (size_t)N * 256;     // N*256 bf16 (dead before layers)
    unsigned short* el = T;                         // E*128 bf16 (layers)
    int*   rank = (int*)agg;                        // E ints, dead before agg first write
    unsigned short* ga = hdb;                       // bf16 N*128, written after csr_gather
    float* h1 = agg;                                // N*128 f32, written after agg last read

    // bf16 weight buffer offsets
    unsigned short* wb_le2  = wbuf;                 // 16384
    unsigned short* wb_geom = wbuf + 16384;         // 3*16384
    unsigned short* wb_down = wbuf + 65536;         // 3*32768
    unsigned short* wb_up   = wbuf + 163840;        // 3*32768
    unsigned short* wb_lin  = wbuf + 262144;        // 65536
    unsigned short* wb_lin2 = wbuf + 327680;        // 65536
    unsigned short* wb_o1   = wbuf + 393216;        // 32768
    unsigned short* wb_cat  = wbuf + 425984;        // 8192

    const int mbE = (E + 127) / 128;
    const int mbN = (N + 127) / 128;
    dim3 blk(256);

    // weight conversions (one fused launch) + wcat + eapad
    cvt_all<<<dim3(1664), blk, 0, stream>>>(
        le2w, geomw, downw, upw, linw, lin2w, o1w, wbuf);
    build_wcat<<<dim3(32), blk, 0, stream>>>(le1w, le12w, le1b, le12b, wb_cat, bcat);
    build_eapad<<<dim3((E * 8 + 255) / 256), blk, 0, stream>>>(
        rel_pos, edge_attr, eapad, E);

    // counting sort by dst
    hipMemsetAsync(cnt, 0, (size_t)N * sizeof(int), stream);
    edge_hist<<<dim3(3125), blk, 0, stream>>>(edst, cnt, E);
    scan_excl<<<dim3(1), dim3(1024), 0, stream>>>(cnt, N);
    edge_rank<<<dim3(3125), blk, 0, stream>>>(esrc, edst, cnt, rank, src_s, E);

    // fused edge embedding (permuted into dst-sorted order)
    edge_embed_fused<<<dim3(mbE), blk, 0, stream>>>(
        eapad, wb_cat, bcat, wb_le2, le2b, rank, ebf, E);

    // node embedding: hb0b -> t1b -> h  (bf16 activations; hb0b aliases eapad)
    node_gather<<<dim3((N + 3) / 4), blk, 0, stream>>>(z, tag, embw, tembw, hb0b, N);
    mgemm<256, A_BF16, ME_STORE_BF16, false><<<dim3(mbN, 2), blk, 0, stream>>>(
        hb0b, wb_lin, linb, nullptr, t1b, N, 256, nullptr);
    mgemm<256, A_BF16, ME_STORE_F32, false><<<dim3(mbN, 2), blk, 0, stream>>>(
        t1b, wb_lin2, lin2b, h, nullptr, N, 256, nullptr);

    // interaction blocks
    for (int l = 0; l < 3; ++l) {
        mgemm<256, A_F32, ME_STORE_BF16, false><<<dim3(mbN, 1), blk, 0, stream>>>(
            h, wb_down + (size_t)l * 32768, downb + (size_t)l * 128,
            nullptr, hdb, N, 128, nullptr);
        mgemm_bs<ME_STORE_BF16><<<dim3(mbE, 1), blk, 0, stream>>>(
            ebf, wb_geom + (size_t)l * 16384, geomb + (size_t)l * 128,
            nullptr, el, E, 128);
        csr_gather<<<dim3((N + 3) / 4), blk, 0, stream>>>(
            (const unsigned int*)el, (const unsigned int*)hdb, src_s, cnt, agg, N);
        hipMemsetAsync(stats, 0, 256 * sizeof(float), stream);
        gn_stats<<<dim3(256), blk, 0, stream>>>(agg, stats, N);
        gn_finalize<<<dim3(1), dim3(128), 0, stream>>>(
            stats, gnw + (size_t)l * 128, gnb + (size_t)l * 128,
            gnms + (size_t)l * 128, ab, 1.0f / (float)N);
        gn_apply<<<dim3(512), blk, 0, stream>>>(agg, ab, (unsigned int*)ga, N * 64);
        mgemm_bs<ME_RESID><<<dim3(mbN, 2), blk, 0, stream>>>(
            ga, wb_up + (size_t)l * 32768, upb + (size_t)l * 256,
            h, nullptr, N, 256);
    }

    // readout
    mgemm<256, A_F32, ME_STORE_F32, false><<<dim3(mbN, 1), blk, 0, stream>>>(
        h, wb_o1, o1b, h1, nullptr, N, 128, nullptr);
    hipMemsetAsync(d_out, 0, 32 * sizeof(float), stream);
    out_reduce<<<dim3(512), blk, 0, stream>>>(h1, o2w, o2b, batch, (float*)d_out, N);
}